// Round 1
// baseline (383.888 us; speedup 1.0000x reference)
//
#include <hip/hip_runtime.h>

typedef unsigned short ushort_t;
typedef unsigned int uint_t;
typedef __bf16 bf16x8 __attribute__((ext_vector_type(8)));
typedef float f32x4 __attribute__((ext_vector_type(4)));
typedef unsigned int u32x4 __attribute__((ext_vector_type(4)));
typedef unsigned short u16x4 __attribute__((ext_vector_type(4)));

#define B_SZ 32
#define N_SZ 512
#define FD_SZ 768
#define HD_SZ 384
#define G_SZ 3
#define M_SZ (B_SZ * N_SZ)   // 16384
#define ALPHA_LR 0.2f
#define NEGV -9.0e15f
#define VTILE (HD_SZ * 32)   // elements per (g,b,jt) V-tile: 384 d x 32 j

__device__ __forceinline__ float bflo(uint_t u) { return __uint_as_float(u << 16); }
__device__ __forceinline__ float bfhi(uint_t u) { return __uint_as_float(u & 0xffff0000u); }
__device__ __forceinline__ float bf2f(ushort_t u) { return __uint_as_float(((uint_t)u) << 16); }
__device__ __forceinline__ ushort_t f2bf(float f) {
  uint_t x = __float_as_uint(f);
  return (ushort_t)((x + 0x7fffu + ((x >> 16) & 1u)) >> 16);
}
__device__ __forceinline__ u32x4 pack8(f32x4 lo, f32x4 hi) {
  union { ushort_t us[8]; u32x4 v; } pk;
  pk.us[0] = f2bf(lo.x); pk.us[1] = f2bf(lo.y); pk.us[2] = f2bf(lo.z); pk.us[3] = f2bf(lo.w);
  pk.us[4] = f2bf(hi.x); pk.us[5] = f2bf(hi.y); pk.us[6] = f2bf(hi.z); pk.us[7] = f2bf(hi.w);
  return pk.v;
}

// ---------------------------------------------------------------------------
// Transpose + downcast: dst[c*R + r] = bf16(src[r*C + c]), batched over z.
// ---------------------------------------------------------------------------
__global__ __launch_bounds__(256) void transpose_f2b(
    const float* __restrict__ src, ushort_t* __restrict__ dst, int R, int C) {
  size_t total = (size_t)R * C;
  size_t base = (size_t)blockIdx.z * total;
  size_t i = (size_t)blockIdx.x * 256 + threadIdx.x;
  if (i < total) {
    int r = (int)(i / C), c = (int)(i % C);
    dst[base + (size_t)c * R + r] = f2bf(src[base + i]);
  }
}

// ---------------------------------------------------------------------------
// Pack adjacency ints (0/1) into bitmask words: am[i>>5] bit (i&31) = adj[i]!=0
// 786432 ints -> 24576 u32 (96 KB). One ballot per wave, 2 word stores.
// ---------------------------------------------------------------------------
__global__ __launch_bounds__(256) void pack_adj(
    const int* __restrict__ adj, uint_t* __restrict__ am) {
  size_t i = (size_t)blockIdx.x * 256 + threadIdx.x;
  unsigned long long mask = __ballot(adj[i] != 0);
  int lane = threadIdx.x & 63;
  if ((lane & 31) == 0) am[i >> 5] = (uint_t)(mask >> (lane & 32));
}

// ---------------------------------------------------------------------------
// Content gates: cg[n][g] = softmax_g( mean_b(x[b,n,:]) @ gate_w + gate_b )
// ---------------------------------------------------------------------------
__global__ __launch_bounds__(256) void gate_kernel(
    const float* __restrict__ x, const float* __restrict__ gate_w,
    const float* __restrict__ gate_b, float* __restrict__ cg) {
  int n = blockIdx.x;
  int tid = threadIdx.x;
  float a0 = 0.f, a1 = 0.f, a2 = 0.f;
  for (int f = tid; f < FD_SZ; f += 256) {
    float s = 0.f;
#pragma unroll
    for (int b = 0; b < B_SZ; b++) s += x[((size_t)b * N_SZ + n) * FD_SZ + f];
    float avg = s * (1.0f / B_SZ);
    a0 += avg * gate_w[f * 3 + 0];
    a1 += avg * gate_w[f * 3 + 1];
    a2 += avg * gate_w[f * 3 + 2];
  }
  for (int m = 1; m < 64; m <<= 1) {
    a0 += __shfl_xor(a0, m, 64);
    a1 += __shfl_xor(a1, m, 64);
    a2 += __shfl_xor(a2, m, 64);
  }
  __shared__ float red[3][4];
  int wave = tid >> 6, lane = tid & 63;
  if (lane == 0) { red[0][wave] = a0; red[1][wave] = a1; red[2][wave] = a2; }
  __syncthreads();
  if (tid == 0) {
    float l0 = red[0][0] + red[0][1] + red[0][2] + red[0][3] + gate_b[0];
    float l1 = red[1][0] + red[1][1] + red[1][2] + red[1][3] + gate_b[1];
    float l2 = red[2][0] + red[2][1] + red[2][2] + red[2][3] + gate_b[2];
    float mx = fmaxf(l0, fmaxf(l1, l2));
    float e0 = __expf(l0 - mx), e1 = __expf(l1 - mx), e2 = __expf(l2 - mx);
    float inv = 1.0f / (e0 + e1 + e2);
    cg[n * 3 + 0] = e0 * inv;
    cg[n * 3 + 1] = e1 * inv;
    cg[n * 3 + 2] = e2 * inv;
  }
}

// ---------------------------------------------------------------------------
// MFMA bf16 GEMM: C[M,Nc] = A[M,K] @ B[K,Nc] (+bias, +relu).
// A row-major [M,K]: f32 (downcast in staging) if AF32, else bf16.
// Bt row-major [Nc,K] bf16. 128x128 tile, BK=32, 4 waves 64x64 each.
// VFOUT: write C as V-tiles vf[(z*32+b)*16+jt][d=0..384)[j2=0..32) bf16,
//        where m = b*512 + jt*32 + j2, n = d. (B-frag-native layout.)
// ---------------------------------------------------------------------------
template <bool AF32, bool RELU, bool OUTBF16, bool HASBIAS, bool VFOUT>
__global__ __launch_bounds__(256) void gemm_kernel(
    const void* __restrict__ Av, size_t strideA,
    const ushort_t* __restrict__ Bt, size_t strideB,
    const float* __restrict__ bias,
    void* __restrict__ Cv, size_t strideC,
    int M, int K, int Nc) {
  __shared__ __attribute__((aligned(16))) ushort_t As[128 * 32];
  __shared__ __attribute__((aligned(16))) ushort_t Bs[128 * 32];
  int tid = threadIdx.x, wave = tid >> 6, lane = tid & 63;
  int m0 = blockIdx.y * 128, n0 = blockIdx.x * 128;
  const float* Abf32 = (const float*)Av + (size_t)blockIdx.z * strideA;
  const ushort_t* Abb16 = (const ushort_t*)Av + (size_t)blockIdx.z * strideA;
  const ushort_t* Bb = Bt + (size_t)blockIdx.z * strideB;

  f32x4 acc[4][4];
  f32x4 z4 = {0.f, 0.f, 0.f, 0.f};
#pragma unroll
  for (int i = 0; i < 4; i++)
#pragma unroll
    for (int j = 0; j < 4; j++) acc[i][j] = z4;

  int wm = (wave & 1) * 64, wn = (wave >> 1) * 64;
  int srow = lane >> 2, schk = (lane & 3) * 8;

  for (int kt = 0; kt < K; kt += 32) {
    u32x4 av[2], bv[2];
#pragma unroll
    for (int i = 0; i < 2; i++) {
      int row = m0 + wave * 32 + i * 16 + srow;
      if (AF32) {
        const float* ap = Abf32 + (size_t)row * K + kt + schk;
        f32x4 lo = *(const f32x4*)ap;
        f32x4 hi = *(const f32x4*)(ap + 4);
        av[i] = pack8(lo, hi);
      } else {
        av[i] = *(const u32x4*)(Abb16 + (size_t)row * K + kt + schk);
      }
      bv[i] = *(const u32x4*)(Bb + (size_t)(n0 + wave * 32 + i * 16 + srow) * K + kt + schk);
    }
    __syncthreads();  // previous tile's frag reads done
#pragma unroll
    for (int i = 0; i < 2; i++) {
      int rowBase = wave * 32 + i * 16;
      *(u32x4*)(As + rowBase * 32 + lane * 8) = av[i];
      *(u32x4*)(Bs + rowBase * 32 + lane * 8) = bv[i];
    }
    __syncthreads();
    bf16x8 af[4], bfr[4];
#pragma unroll
    for (int t = 0; t < 4; t++) {
      af[t] = *(const bf16x8*)(As + (wm + t * 16 + (lane & 15)) * 32 + (lane >> 4) * 8);
      bfr[t] = *(const bf16x8*)(Bs + (wn + t * 16 + (lane & 15)) * 32 + (lane >> 4) * 8);
    }
#pragma unroll
    for (int mt = 0; mt < 4; mt++)
#pragma unroll
      for (int nt = 0; nt < 4; nt++)
        acc[mt][nt] = __builtin_amdgcn_mfma_f32_16x16x32_bf16(af[mt], bfr[nt], acc[mt][nt], 0, 0, 0);
  }

  if (VFOUT) {
    // per lane: 4 consecutive m at fixed n=d -> one 8B store inside a V-tile
#pragma unroll
    for (int mt = 0; mt < 4; mt++) {
#pragma unroll
      for (int nt = 0; nt < 4; nt++) {
        int d = n0 + wn + nt * 16 + (lane & 15);
        int gm = m0 + wm + mt * 16 + (lane >> 4) * 4;
        int b = gm >> 9, jt = (gm >> 5) & 15, j2 = gm & 31;
        u16x4 pk;
#pragma unroll
        for (int r2 = 0; r2 < 4; r2++) pk[r2] = f2bf(acc[mt][nt][r2]);
        size_t off = ((size_t)((blockIdx.z * B_SZ + b) * 16 + jt)) * VTILE + (size_t)d * 32 + j2;
        *(u16x4*)((ushort_t*)Cv + off) = pk;
      }
    }
  } else {
#pragma unroll
    for (int mt = 0; mt < 4; mt++) {
#pragma unroll
      for (int nt = 0; nt < 4; nt++) {
        int gn = n0 + wn + nt * 16 + (lane & 15);
        float bvs = HASBIAS ? bias[gn] : 0.f;
#pragma unroll
        for (int r2 = 0; r2 < 4; r2++) {
          int gm = m0 + wm + mt * 16 + (lane >> 4) * 4 + r2;
          float v = acc[mt][nt][r2] + bvs;
          if (RELU) v = v > 0.f ? v : 0.f;
          size_t off = (size_t)blockIdx.z * strideC + (size_t)gm * Nc + gn;
          if (OUTBF16) ((ushort_t*)Cv)[off] = f2bf(v);
          else ((float*)Cv)[off] = v;
        }
      }
    }
  }
}

// ---------------------------------------------------------------------------
// e1[g,m] = sum_d V[g][m][d]*a1[d];  e2 likewise. V in tiled vf layout.
// grid: (M/256, G); thread -> m, reads stride-32-elem columns (64B granular).
// ---------------------------------------------------------------------------
__global__ __launch_bounds__(256) void e12_kernel(
    const ushort_t* __restrict__ vf, const float* __restrict__ a,
    float* __restrict__ e1, float* __restrict__ e2) {
  __shared__ float a1s[HD_SZ], a2s[HD_SZ];
  int g = blockIdx.y;
  int tid = threadIdx.x;
  for (int i = tid; i < HD_SZ; i += 256) {
    a1s[i] = a[g * 2 * HD_SZ + i];
    a2s[i] = a[g * 2 * HD_SZ + HD_SZ + i];
  }
  __syncthreads();
  int m = blockIdx.x * 256 + tid;
  int b = m >> 9, jt = (m >> 5) & 15, j2 = m & 31;
  const ushort_t* col = vf + ((size_t)((g * B_SZ + b) * 16 + jt)) * VTILE + j2;
  float s1 = 0.f, s2 = 0.f;
  for (int d = 0; d < HD_SZ; d++) {
    float h = bf2f(col[d * 32]);
    s1 += h * a1s[d];
    s2 += h * a2s[d];
  }
  e1[(size_t)g * M_SZ + m] = s1;
  e2[(size_t)g * M_SZ + m] = s2;
}

// ---------------------------------------------------------------------------
// Attention (MFMA PV) + ELU + LN1 + g-weighted fuse.
// 512 threads / 8 waves per block (was 4): wave w owns d in [w*48, w*48+48)
// and softmax rows {2w, 2w+1}. Doubles resident waves/CU (occupancy was 27%,
// kernel latency-bound with all pipes idle). adj consumed as LDS-staged
// bitmask (1 KB per g) instead of 32 strided 4B VMEM loads per lane.
// ---------------------------------------------------------------------------
__global__ __launch_bounds__(512, 8) void attn_kernel(
    const uint_t* __restrict__ adjm, const ushort_t* __restrict__ vf,
    const float* __restrict__ e1, const float* __restrict__ e2,
    const float* __restrict__ cg, const float* __restrict__ log_unc,
    const float* __restrict__ ln1g, const float* __restrict__ ln1b,
    ushort_t* __restrict__ fusedbf) {
  __shared__ __attribute__((aligned(16))) ushort_t Pb[16][520];  // +8 pad
  __shared__ float e2s[512];
  __shared__ float e1r[16];
  __shared__ uint_t amS[16][16];
  __shared__ float lng[HD_SZ], lnb[HD_SZ];
  __shared__ float cgr[16][3];
  __shared__ float s1s[16][8], s2s[16][8];

  int tid = threadIdx.x, wave = tid >> 6, lane = tid & 63;
  int quad = lane >> 4, l15 = lane & 15;
  int b = blockIdx.y, i0 = blockIdx.x * 16;

  float iv0 = 1.f / (__expf(log_unc[0]) + 1e-8f);
  float iv1 = 1.f / (__expf(log_unc[1]) + 1e-8f);
  float iv2 = 1.f / (__expf(log_unc[2]) + 1e-8f);
  float mxa = fmaxf(iv0, fmaxf(iv1, iv2));
  float w0 = __expf(iv0 - mxa), w1 = __expf(iv1 - mxa), w2 = __expf(iv2 - mxa);
  float wsum = 1.f / (w0 + w1 + w2);
  float attw[3] = {w0 * wsum, w1 * wsum, w2 * wsum};

  for (int idx = tid; idx < HD_SZ; idx += 512) {
    lng[idx] = ln1g[idx];
    lnb[idx] = ln1b[idx];
  }
  if (tid < 48) cgr[tid / 3][tid % 3] = cg[(i0 + tid / 3) * 3 + tid % 3];

  float facc[12];
#pragma unroll
  for (int t = 0; t < 12; t++) facc[t] = 0.f;

  for (int g = 0; g < G_SZ; g++) {
    __syncthreads();  // previous iteration's LDS readers done
    if (tid < 16) e1r[tid] = e1[((size_t)g * B_SZ + b) * N_SZ + i0 + tid];
    if (tid < 256)
      amS[tid >> 4][tid & 15] = adjm[((size_t)g * N_SZ + i0 + (tid >> 4)) * 16 + (tid & 15)];
    for (int idx = tid; idx < N_SZ; idx += 512)
      e2s[idx] = e2[((size_t)g * B_SZ + b) * N_SZ + idx];
    __syncthreads();

    // scores + softmax, in-register; wave owns rows {2*wave, 2*wave+1}
#pragma unroll
    for (int rr = 0; rr < 2; rr++) {
      int rw = wave * 2 + rr;
      float e1v = e1r[rw];
      float sv[8];
      float m = -3.0e38f;
#pragma unroll
      for (int jj = 0; jj < 8; jj++) {
        int j = lane + jj * 64;
        float s = e1v + e2s[j];
        s = s > 0.f ? s : ALPHA_LR * s;
        uint_t mw = amS[rw][(lane >> 5) + jj * 2];  // broadcast per half-wave
        s = ((mw >> (j & 31)) & 1u) ? s : NEGV;
        sv[jj] = s;
        m = fmaxf(m, s);
      }
      for (int msk = 1; msk < 64; msk <<= 1) m = fmaxf(m, __shfl_xor(m, msk, 64));
      float sum = 0.f;
#pragma unroll
      for (int jj = 0; jj < 8; jj++) {
        float e = __expf(sv[jj] - m);
        sv[jj] = e;
        sum += e;
      }
      for (int msk = 1; msk < 64; msk <<= 1) sum += __shfl_xor(sum, msk, 64);
      float inv = 1.0f / sum;
#pragma unroll
      for (int jj = 0; jj < 8; jj++) Pb[rw][lane + jj * 64] = f2bf(sv[jj] * inv);
    }
    __syncthreads();

    // PV via MFMA: O[16 x 48-per-wave] = P[16 x 512] @ V
    f32x4 acc[3];
    f32x4 z4 = {0.f, 0.f, 0.f, 0.f};
#pragma unroll
    for (int t = 0; t < 3; t++) acc[t] = z4;
    const ushort_t* vbase = vf + ((size_t)(g * B_SZ + b) * 16) * VTILE;
    for (int j0 = 0; j0 < N_SZ; j0 += 32) {
      bf16x8 af = *(const bf16x8*)(&Pb[l15][j0 + quad * 8]);
      const ushort_t* vtile = vbase + (size_t)(j0 >> 5) * VTILE;
#pragma unroll
      for (int t = 0; t < 3; t++) {
        bf16x8 bf = *(const bf16x8*)(vtile + (wave * 48 + t * 16 + l15) * 32 + quad * 8);
        acc[t] = __builtin_amdgcn_mfma_f32_16x16x32_bf16(af, bf, acc[t], 0, 0, 0);
      }
    }

    // epilogue: ELU, LN over HD per query row (row = quad*4+r), weight, accum
    float o[12];
    float ps1[4] = {0.f, 0.f, 0.f, 0.f}, ps2[4] = {0.f, 0.f, 0.f, 0.f};
#pragma unroll
    for (int t = 0; t < 3; t++)
#pragma unroll
      for (int r = 0; r < 4; r++) {
        float v = acc[t][r];
        v = v > 0.f ? v : __expf(v) - 1.f;
        o[t * 4 + r] = v;
        ps1[r] += v;
        ps2[r] += v * v;
      }
#pragma unroll
    for (int msk = 1; msk < 16; msk <<= 1) {
#pragma unroll
      for (int r = 0; r < 4; r++) {
        ps1[r] += __shfl_xor(ps1[r], msk, 64);
        ps2[r] += __shfl_xor(ps2[r], msk, 64);
      }
    }
    if (l15 == 0) {
#pragma unroll
      for (int r = 0; r < 4; r++) {
        s1s[quad * 4 + r][wave] = ps1[r];
        s2s[quad * 4 + r][wave] = ps2[r];
      }
    }
    __syncthreads();
#pragma unroll
    for (int r = 0; r < 4; r++) {
      int row = quad * 4 + r;
      float S1 = 0.f, S2 = 0.f;
#pragma unroll
      for (int w = 0; w < 8; w++) {
        S1 += s1s[row][w];
        S2 += s2s[row][w];
      }
      float mean = S1 * (1.f / HD_SZ);
      float var = S2 * (1.f / HD_SZ) - mean * mean;
      float rs = rsqrtf(var + 1e-5f);
      float wgt = 0.7f * attw[g] + 0.3f * cgr[row][g];
#pragma unroll
      for (int t = 0; t < 3; t++) {
        int d = wave * 48 + t * 16 + l15;
        facc[t * 4 + r] += wgt * ((o[t * 4 + r] - mean) * rs * lng[d] + lnb[d]);
      }
    }
  }
  // write fused bf16 [b][i0+row][d]
#pragma unroll
  for (int r = 0; r < 4; r++) {
    size_t rowo = ((size_t)b * N_SZ + i0 + quad * 4 + r) * HD_SZ;
#pragma unroll
    for (int t = 0; t < 3; t++)
      fusedbf[rowo + wave * 48 + t * 16 + l15] = f2bf(facc[t * 4 + r]);
  }
}

// ---------------------------------------------------------------------------
// LN2 + residual sigmoid gate. One block per (b,n) row. proj bf16, x/out f32.
// ---------------------------------------------------------------------------
__global__ __launch_bounds__(256) void final_kernel(
    const ushort_t* __restrict__ projbf, const float* __restrict__ x,
    const float* __restrict__ ln2g, const float* __restrict__ ln2b,
    float* __restrict__ out) {
  int row = blockIdx.x;
  int tid = threadIdx.x, wave = tid >> 6, lane = tid & 63;
  const ushort_t* pr = projbf + (size_t)row * FD_SZ;
  const float* xr = x + (size_t)row * FD_SZ;
  float v[3], xv[3];
  float s1 = 0.f, s2 = 0.f;
#pragma unroll
  for (int k = 0; k < 3; k++) {
    int c = tid + k * 256;
    v[k] = bf2f(pr[c]);
    xv[k] = xr[c];
    s1 += v[k];
    s2 += v[k] * v[k];
  }
  for (int m = 1; m < 64; m <<= 1) {
    s1 += __shfl_xor(s1, m, 64);
    s2 += __shfl_xor(s2, m, 64);
  }
  __shared__ float rs1[4], rs2[4], rdt[4];
  if (lane == 0) { rs1[wave] = s1; rs2[wave] = s2; }
  __syncthreads();
  s1 = rs1[0] + rs1[1] + rs1[2] + rs1[3];
  s2 = rs2[0] + rs2[1] + rs2[2] + rs2[3];
  float mean = s1 * (1.f / FD_SZ);
  float var = s2 * (1.f / FD_SZ) - mean * mean;
  float rstd = rsqrtf(var + 1e-5f);
  float dot = 0.f;
  float pn[3];
#pragma unroll
  for (int k = 0; k < 3; k++) {
    int c = tid + k * 256;
    pn[k] = (v[k] - mean) * rstd * ln2g[c] + ln2b[c];
    dot += pn[k] * xv[k];
  }
  for (int m = 1; m < 64; m <<= 1) dot += __shfl_xor(dot, m, 64);
  if (lane == 0) rdt[wave] = dot;
  __syncthreads();
  dot = rdt[0] + rdt[1] + rdt[2] + rdt[3];
  float gv = 1.f / (1.f + __expf(-dot * (1.0f / 27.712812921102035f)));  // /sqrt(768)
#pragma unroll
  for (int k = 0; k < 3; k++) {
    int c = tid + k * 256;
    out[(size_t)row * FD_SZ + c] = gv * xv[k] + (1.f - gv) * pn[k];
  }
}

// ---------------------------------------------------------------------------
extern "C" void kernel_launch(void* const* d_in, const int* in_sizes, int n_in,
                              void* d_out, int out_size, void* d_ws, size_t ws_size,
                              hipStream_t stream) {
  (void)in_sizes; (void)n_in; (void)out_size; (void)ws_size;
  const float* x = (const float*)d_in[0];
  const int* adj = (const int*)d_in[1];
  const float* W = (const float*)d_in[2];
  const float* a = (const float*)d_in[3];
  const float* log_unc = (const float*)d_in[4];
  const float* gate_w = (const float*)d_in[5];
  const float* gate_b = (const float*)d_in[6];
  const float* ln1g = (const float*)d_in[7];
  const float* ln1b = (const float*)d_in[8];
  const float* w1 = (const float*)d_in[9];
  const float* b1 = (const float*)d_in[10];
  const float* w2 = (const float*)d_in[11];
  const float* b2 = (const float*)d_in[12];
  const float* ln2g = (const float*)d_in[13];
  const float* ln2b = (const float*)d_in[14];

  // Workspace (peak 53,385,216 B ≈ 50.9 MiB, liveness-overlapped):
  //  [0          ) Wt      1,769,472   (bf16 [G][HD][FD]); after vf GEMM the
  //                 region is dead -> adjm (98,304 B bitmask) reuses offset 0
  //  [1,769,472  ) w1t     294,912
  //  [2,064,384  ) w2t     589,824
  //  [2,654,208  ) cg      6,144
  //  [2,660,352  ) e1      196,608
  //  [2,856,960  ) e2      196,608
  //  [3,053,568  ) fusedbf 12,582,912  (attn -> t1 GEMM)
  //  [15,636,480 ) vf      37,748,736  (tiled V; h GEMM -> attn); reused:
  //  [15,636,480 )   t1bf    12,582,912
  //  [28,219,392 )   projbf  25,165,824
  char* ws = (char*)d_ws;
  ushort_t* Wt      = (ushort_t*)(ws + 0);
  uint_t*   adjm    = (uint_t*)(ws + 0);            // over dead Wt (post-vf)
  ushort_t* w1t     = (ushort_t*)(ws + 1769472);
  ushort_t* w2t     = (ushort_t*)(ws + 2064384);
  float*    cg      = (float*)(ws + 2654208);
  float*    e1      = (float*)(ws + 2660352);
  float*    e2      = (float*)(ws + 2856960);
  ushort_t* fusedbf = (ushort_t*)(ws + 3053568);
  ushort_t* vf      = (ushort_t*)(ws + 15636480);
  ushort_t* t1bf    = (ushort_t*)(ws + 15636480);   // over dead vf
  ushort_t* projbf  = (ushort_t*)(ws + 28219392);   // over dead vf

  transpose_f2b<<<dim3(1152, 1, 3), 256, 0, stream>>>(W, Wt, FD_SZ, HD_SZ);
  transpose_f2b<<<dim3(576, 1, 1), 256, 0, stream>>>(w1, w1t, HD_SZ, HD_SZ);
  transpose_f2b<<<dim3(1152, 1, 1), 256, 0, stream>>>(w2, w2t, HD_SZ, FD_SZ);

  gate_kernel<<<dim3(N_SZ), 256, 0, stream>>>(x, gate_w, gate_b, cg);

  // vf[g] = (x @ W[g]) in V-tile layout, written from the C-fragments
  gemm_kernel<true, false, true, false, true><<<dim3(3, 128, 3), 256, 0, stream>>>(
      x, 0, Wt, (size_t)HD_SZ * FD_SZ, nullptr, vf, 0,
      M_SZ, FD_SZ, HD_SZ);

  // adj -> bitmask, into the now-dead Wt region (must follow the vf GEMM)
  pack_adj<<<dim3((G_SZ * N_SZ * N_SZ) / 256), 256, 0, stream>>>(adj, adjm);

  e12_kernel<<<dim3(M_SZ / 256, G_SZ), 256, 0, stream>>>(vf, a, e1, e2);

  attn_kernel<<<dim3(N_SZ / 16, B_SZ), 512, 0, stream>>>(
      adjm, vf, e1, e2, cg, log_unc, ln1g, ln1b, fusedbf);

  // t1 = relu(fused @ w1 + b1)
  gemm_kernel<false, true, true, true, false><<<dim3(3, 128, 1), 256, 0, stream>>>(
      fusedbf, 0, w1t, 0, b1, t1bf, 0, M_SZ, HD_SZ, HD_SZ);
  // proj = t1 @ w2 + b2 (bf16 out)
  gemm_kernel<false, false, true, true, false><<<dim3(6, 128, 1), 256, 0, stream>>>(
      t1bf, 0, w2t, 0, b2, projbf, 0, M_SZ, HD_SZ, FD_SZ);

  final_kernel<<<dim3(M_SZ), 256, 0, stream>>>(projbf, x, ln2g, ln2b, (float*)d_out);
}

// Round 2
// 372.243 us; speedup vs baseline: 1.0313x; 1.0313x over previous
//
#include <hip/hip_runtime.h>

typedef unsigned short ushort_t;
typedef unsigned int uint_t;
typedef __bf16 bf16x8 __attribute__((ext_vector_type(8)));
typedef float f32x4 __attribute__((ext_vector_type(4)));
typedef unsigned int u32x4 __attribute__((ext_vector_type(4)));
typedef unsigned short u16x4 __attribute__((ext_vector_type(4)));

#define B_SZ 32
#define N_SZ 512
#define FD_SZ 768
#define HD_SZ 384
#define G_SZ 3
#define M_SZ (B_SZ * N_SZ)   // 16384
#define ALPHA_LR 0.2f
#define NEGV -9.0e15f
#define VTILE (HD_SZ * 32)   // elements per (g,b,jt) V-tile: 384 d x 32 j

__device__ __forceinline__ float bflo(uint_t u) { return __uint_as_float(u << 16); }
__device__ __forceinline__ float bfhi(uint_t u) { return __uint_as_float(u & 0xffff0000u); }
__device__ __forceinline__ float bf2f(ushort_t u) { return __uint_as_float(((uint_t)u) << 16); }
__device__ __forceinline__ ushort_t f2bf(float f) {
  uint_t x = __float_as_uint(f);
  return (ushort_t)((x + 0x7fffu + ((x >> 16) & 1u)) >> 16);
}
__device__ __forceinline__ u32x4 pack8(f32x4 lo, f32x4 hi) {
  union { ushort_t us[8]; u32x4 v; } pk;
  pk.us[0] = f2bf(lo.x); pk.us[1] = f2bf(lo.y); pk.us[2] = f2bf(lo.z); pk.us[3] = f2bf(lo.w);
  pk.us[4] = f2bf(hi.x); pk.us[5] = f2bf(hi.y); pk.us[6] = f2bf(hi.z); pk.us[7] = f2bf(hi.w);
  return pk.v;
}

// ---------------------------------------------------------------------------
// Transpose + downcast: dst[c*R + r] = bf16(src[r*C + c]), batched over z.
// ---------------------------------------------------------------------------
__global__ __launch_bounds__(256) void transpose_f2b(
    const float* __restrict__ src, ushort_t* __restrict__ dst, int R, int C) {
  size_t total = (size_t)R * C;
  size_t base = (size_t)blockIdx.z * total;
  size_t i = (size_t)blockIdx.x * 256 + threadIdx.x;
  if (i < total) {
    int r = (int)(i / C), c = (int)(i % C);
    dst[base + (size_t)c * R + r] = f2bf(src[base + i]);
  }
}

// ---------------------------------------------------------------------------
// Pack adjacency ints (0/1) into bitmask words: am[i>>5] bit (i&31) = adj[i]!=0
// ---------------------------------------------------------------------------
__global__ __launch_bounds__(256) void pack_adj(
    const int* __restrict__ adj, uint_t* __restrict__ am) {
  size_t i = (size_t)blockIdx.x * 256 + threadIdx.x;
  unsigned long long mask = __ballot(adj[i] != 0);
  int lane = threadIdx.x & 63;
  if ((lane & 31) == 0) am[i >> 5] = (uint_t)(mask >> (lane & 32));
}

// ---------------------------------------------------------------------------
// Content gates: cg[n][g] = softmax_g( mean_b(x[b,n,:]) @ gate_w + gate_b )
// ---------------------------------------------------------------------------
__global__ __launch_bounds__(256) void gate_kernel(
    const float* __restrict__ x, const float* __restrict__ gate_w,
    const float* __restrict__ gate_b, float* __restrict__ cg) {
  int n = blockIdx.x;
  int tid = threadIdx.x;
  float a0 = 0.f, a1 = 0.f, a2 = 0.f;
  for (int f = tid; f < FD_SZ; f += 256) {
    float s = 0.f;
#pragma unroll
    for (int b = 0; b < B_SZ; b++) s += x[((size_t)b * N_SZ + n) * FD_SZ + f];
    float avg = s * (1.0f / B_SZ);
    a0 += avg * gate_w[f * 3 + 0];
    a1 += avg * gate_w[f * 3 + 1];
    a2 += avg * gate_w[f * 3 + 2];
  }
  for (int m = 1; m < 64; m <<= 1) {
    a0 += __shfl_xor(a0, m, 64);
    a1 += __shfl_xor(a1, m, 64);
    a2 += __shfl_xor(a2, m, 64);
  }
  __shared__ float red[3][4];
  int wave = tid >> 6, lane = tid & 63;
  if (lane == 0) { red[0][wave] = a0; red[1][wave] = a1; red[2][wave] = a2; }
  __syncthreads();
  if (tid == 0) {
    float l0 = red[0][0] + red[0][1] + red[0][2] + red[0][3] + gate_b[0];
    float l1 = red[1][0] + red[1][1] + red[1][2] + red[1][3] + gate_b[1];
    float l2 = red[2][0] + red[2][1] + red[2][2] + red[2][3] + gate_b[2];
    float mx = fmaxf(l0, fmaxf(l1, l2));
    float e0 = __expf(l0 - mx), e1 = __expf(l1 - mx), e2 = __expf(l2 - mx);
    float inv = 1.0f / (e0 + e1 + e2);
    cg[n * 3 + 0] = e0 * inv;
    cg[n * 3 + 1] = e1 * inv;
    cg[n * 3 + 2] = e2 * inv;
  }
}

// ---------------------------------------------------------------------------
// MFMA bf16 GEMM: C[M,Nc] = A[M,K] @ B[K,Nc] (+bias, +relu).
// A row-major [M,K]: f32 (downcast in staging) if AF32, else bf16.
// Bt row-major [Nc,K] bf16. 128x128 tile, BK=32, 4 waves 64x64 each.
// VFOUT: write C as V-tiles vf[(z*32+b)*16+jt][d=0..384)[j2=0..32) bf16,
//        where m = b*512 + jt*32 + j2, n = d. (B-frag-native layout.)
// ---------------------------------------------------------------------------
template <bool AF32, bool RELU, bool OUTBF16, bool HASBIAS, bool VFOUT>
__global__ __launch_bounds__(256) void gemm_kernel(
    const void* __restrict__ Av, size_t strideA,
    const ushort_t* __restrict__ Bt, size_t strideB,
    const float* __restrict__ bias,
    void* __restrict__ Cv, size_t strideC,
    int M, int K, int Nc) {
  __shared__ __attribute__((aligned(16))) ushort_t As[128 * 32];
  __shared__ __attribute__((aligned(16))) ushort_t Bs[128 * 32];
  int tid = threadIdx.x, wave = tid >> 6, lane = tid & 63;
  int m0 = blockIdx.y * 128, n0 = blockIdx.x * 128;
  const float* Abf32 = (const float*)Av + (size_t)blockIdx.z * strideA;
  const ushort_t* Abb16 = (const ushort_t*)Av + (size_t)blockIdx.z * strideA;
  const ushort_t* Bb = Bt + (size_t)blockIdx.z * strideB;

  f32x4 acc[4][4];
  f32x4 z4 = {0.f, 0.f, 0.f, 0.f};
#pragma unroll
  for (int i = 0; i < 4; i++)
#pragma unroll
    for (int j = 0; j < 4; j++) acc[i][j] = z4;

  int wm = (wave & 1) * 64, wn = (wave >> 1) * 64;
  int srow = lane >> 2, schk = (lane & 3) * 8;

  for (int kt = 0; kt < K; kt += 32) {
    u32x4 av[2], bv[2];
#pragma unroll
    for (int i = 0; i < 2; i++) {
      int row = m0 + wave * 32 + i * 16 + srow;
      if (AF32) {
        const float* ap = Abf32 + (size_t)row * K + kt + schk;
        f32x4 lo = *(const f32x4*)ap;
        f32x4 hi = *(const f32x4*)(ap + 4);
        av[i] = pack8(lo, hi);
      } else {
        av[i] = *(const u32x4*)(Abb16 + (size_t)row * K + kt + schk);
      }
      bv[i] = *(const u32x4*)(Bb + (size_t)(n0 + wave * 32 + i * 16 + srow) * K + kt + schk);
    }
    __syncthreads();  // previous tile's frag reads done
#pragma unroll
    for (int i = 0; i < 2; i++) {
      int rowBase = wave * 32 + i * 16;
      *(u32x4*)(As + rowBase * 32 + lane * 8) = av[i];
      *(u32x4*)(Bs + rowBase * 32 + lane * 8) = bv[i];
    }
    __syncthreads();
    bf16x8 af[4], bfr[4];
#pragma unroll
    for (int t = 0; t < 4; t++) {
      af[t] = *(const bf16x8*)(As + (wm + t * 16 + (lane & 15)) * 32 + (lane >> 4) * 8);
      bfr[t] = *(const bf16x8*)(Bs + (wn + t * 16 + (lane & 15)) * 32 + (lane >> 4) * 8);
    }
#pragma unroll
    for (int mt = 0; mt < 4; mt++)
#pragma unroll
      for (int nt = 0; nt < 4; nt++)
        acc[mt][nt] = __builtin_amdgcn_mfma_f32_16x16x32_bf16(af[mt], bfr[nt], acc[mt][nt], 0, 0, 0);
  }

  if (VFOUT) {
    // per lane: 4 consecutive m at fixed n=d -> one 8B store inside a V-tile
#pragma unroll
    for (int mt = 0; mt < 4; mt++) {
#pragma unroll
      for (int nt = 0; nt < 4; nt++) {
        int d = n0 + wn + nt * 16 + (lane & 15);
        int gm = m0 + wm + mt * 16 + (lane >> 4) * 4;
        int b = gm >> 9, jt = (gm >> 5) & 15, j2 = gm & 31;
        u16x4 pk;
#pragma unroll
        for (int r2 = 0; r2 < 4; r2++) pk[r2] = f2bf(acc[mt][nt][r2]);
        size_t off = ((size_t)((blockIdx.z * B_SZ + b) * 16 + jt)) * VTILE + (size_t)d * 32 + j2;
        *(u16x4*)((ushort_t*)Cv + off) = pk;
      }
    }
  } else {
#pragma unroll
    for (int mt = 0; mt < 4; mt++) {
#pragma unroll
      for (int nt = 0; nt < 4; nt++) {
        int gn = n0 + wn + nt * 16 + (lane & 15);
        float bvs = HASBIAS ? bias[gn] : 0.f;
#pragma unroll
        for (int r2 = 0; r2 < 4; r2++) {
          int gm = m0 + wm + mt * 16 + (lane >> 4) * 4 + r2;
          float v = acc[mt][nt][r2] + bvs;
          if (RELU) v = v > 0.f ? v : 0.f;
          size_t off = (size_t)blockIdx.z * strideC + (size_t)gm * Nc + gn;
          if (OUTBF16) ((ushort_t*)Cv)[off] = f2bf(v);
          else ((float*)Cv)[off] = v;
        }
      }
    }
  }
}

// ---------------------------------------------------------------------------
// e1[g,m] = sum_d V[g][m][d]*a1[d];  e2 likewise. V in tiled vf layout.
// ---------------------------------------------------------------------------
__global__ __launch_bounds__(256) void e12_kernel(
    const ushort_t* __restrict__ vf, const float* __restrict__ a,
    float* __restrict__ e1, float* __restrict__ e2) {
  __shared__ float a1s[HD_SZ], a2s[HD_SZ];
  int g = blockIdx.y;
  int tid = threadIdx.x;
  for (int i = tid; i < HD_SZ; i += 256) {
    a1s[i] = a[g * 2 * HD_SZ + i];
    a2s[i] = a[g * 2 * HD_SZ + HD_SZ + i];
  }
  __syncthreads();
  int m = blockIdx.x * 256 + tid;
  int b = m >> 9, jt = (m >> 5) & 15, j2 = m & 31;
  const ushort_t* col = vf + ((size_t)((g * B_SZ + b) * 16 + jt)) * VTILE + j2;
  float s1 = 0.f, s2 = 0.f;
  for (int d = 0; d < HD_SZ; d++) {
    float h = bf2f(col[d * 32]);
    s1 += h * a1s[d];
    s2 += h * a2s[d];
  }
  e1[(size_t)g * M_SZ + m] = s1;
  e2[(size_t)g * M_SZ + m] = s2;
}

// ---------------------------------------------------------------------------
// Attention (MFMA PV) + ELU + LN1 + g-weighted fuse.
// 512 threads / 8 waves. launch_bounds(512,4): cap 128 VGPR -> no scratch
// (round-1's (512,8) forced VGPR=32 and spilled ~150 MB/dispatch).
// XCD swizzle: all 32 i0-blocks of one b share (linear id % 8) -> same XCD,
// so each (g,b) V-tile (393 KB) lives in ONE L2 and is re-read 32x from it
// (was: duplicated across 8 XCD L2s, stream served by L3 at ~10 TB/s).
// ---------------------------------------------------------------------------
__global__ __launch_bounds__(512, 4) void attn_kernel(
    const uint_t* __restrict__ adjm, const ushort_t* __restrict__ vf,
    const float* __restrict__ e1, const float* __restrict__ e2,
    const float* __restrict__ cg, const float* __restrict__ log_unc,
    const float* __restrict__ ln1g, const float* __restrict__ ln1b,
    ushort_t* __restrict__ fusedbf) {
  __shared__ __attribute__((aligned(16))) ushort_t Pb[16][520];  // +8 pad
  __shared__ float e2s[512];
  __shared__ float e1r[16];
  __shared__ uint_t amS[16][16];
  __shared__ float lng[HD_SZ], lnb[HD_SZ];
  __shared__ float cgr[16][3];
  __shared__ float s1s[16][8], s2s[16][8];

  int tid = threadIdx.x, wave = tid >> 6, lane = tid & 63;
  int quad = lane >> 4, l15 = lane & 15;
  // XCD-pinning decode: L%8 constant for fixed b => same XCD for all i0 of b
  int L = blockIdx.x + (blockIdx.y << 5);        // gridDim.x == 32
  int b = (L & 7) + ((L >> 8) << 3);
  int i0 = ((L >> 3) & 31) * 16;

  float iv0 = 1.f / (__expf(log_unc[0]) + 1e-8f);
  float iv1 = 1.f / (__expf(log_unc[1]) + 1e-8f);
  float iv2 = 1.f / (__expf(log_unc[2]) + 1e-8f);
  float mxa = fmaxf(iv0, fmaxf(iv1, iv2));
  float w0 = __expf(iv0 - mxa), w1 = __expf(iv1 - mxa), w2 = __expf(iv2 - mxa);
  float wsum = 1.f / (w0 + w1 + w2);
  float attw[3] = {w0 * wsum, w1 * wsum, w2 * wsum};

  for (int idx = tid; idx < HD_SZ; idx += 512) {
    lng[idx] = ln1g[idx];
    lnb[idx] = ln1b[idx];
  }
  if (tid < 48) cgr[tid / 3][tid % 3] = cg[(i0 + tid / 3) * 3 + tid % 3];

  float facc[12];
#pragma unroll
  for (int t = 0; t < 12; t++) facc[t] = 0.f;

  for (int g = 0; g < G_SZ; g++) {
    __syncthreads();  // previous iteration's LDS readers done
    if (tid < 16) e1r[tid] = e1[((size_t)g * B_SZ + b) * N_SZ + i0 + tid];
    if (tid < 256)
      amS[tid >> 4][tid & 15] = adjm[((size_t)g * N_SZ + i0 + (tid >> 4)) * 16 + (tid & 15)];
    for (int idx = tid; idx < N_SZ; idx += 512)
      e2s[idx] = e2[((size_t)g * B_SZ + b) * N_SZ + idx];
    __syncthreads();

    // scores + softmax, in-register; wave owns rows {2*wave, 2*wave+1}
#pragma unroll
    for (int rr = 0; rr < 2; rr++) {
      int rw = wave * 2 + rr;
      float e1v = e1r[rw];
      float sv[8];
      float m = -3.0e38f;
#pragma unroll
      for (int jj = 0; jj < 8; jj++) {
        int j = lane + jj * 64;
        float s = e1v + e2s[j];
        s = s > 0.f ? s : ALPHA_LR * s;
        uint_t mw = amS[rw][(lane >> 5) + jj * 2];  // broadcast per half-wave
        s = ((mw >> (j & 31)) & 1u) ? s : NEGV;
        sv[jj] = s;
        m = fmaxf(m, s);
      }
      for (int msk = 1; msk < 64; msk <<= 1) m = fmaxf(m, __shfl_xor(m, msk, 64));
      float sum = 0.f;
#pragma unroll
      for (int jj = 0; jj < 8; jj++) {
        float e = __expf(sv[jj] - m);
        sv[jj] = e;
        sum += e;
      }
      for (int msk = 1; msk < 64; msk <<= 1) sum += __shfl_xor(sum, msk, 64);
      float inv = 1.0f / sum;
#pragma unroll
      for (int jj = 0; jj < 8; jj++) Pb[rw][lane + jj * 64] = f2bf(sv[jj] * inv);
    }
    __syncthreads();

    // PV via MFMA: O[16 x 48-per-wave] = P[16 x 512] @ V
    f32x4 acc[3];
    f32x4 z4 = {0.f, 0.f, 0.f, 0.f};
#pragma unroll
    for (int t = 0; t < 3; t++) acc[t] = z4;
    const ushort_t* vbase = vf + ((size_t)(g * B_SZ + b) * 16) * VTILE;
#pragma unroll 2
    for (int j0 = 0; j0 < N_SZ; j0 += 32) {
      bf16x8 af = *(const bf16x8*)(&Pb[l15][j0 + quad * 8]);
      const ushort_t* vtile = vbase + (size_t)(j0 >> 5) * VTILE;
#pragma unroll
      for (int t = 0; t < 3; t++) {
        bf16x8 bf = *(const bf16x8*)(vtile + (wave * 48 + t * 16 + l15) * 32 + quad * 8);
        acc[t] = __builtin_amdgcn_mfma_f32_16x16x32_bf16(af, bf, acc[t], 0, 0, 0);
      }
    }

    // epilogue: ELU, LN over HD per query row (row = quad*4+r), weight, accum
    float o[12];
    float ps1[4] = {0.f, 0.f, 0.f, 0.f}, ps2[4] = {0.f, 0.f, 0.f, 0.f};
#pragma unroll
    for (int t = 0; t < 3; t++)
#pragma unroll
      for (int r = 0; r < 4; r++) {
        float v = acc[t][r];
        v = v > 0.f ? v : __expf(v) - 1.f;
        o[t * 4 + r] = v;
        ps1[r] += v;
        ps2[r] += v * v;
      }
#pragma unroll
    for (int msk = 1; msk < 16; msk <<= 1) {
#pragma unroll
      for (int r = 0; r < 4; r++) {
        ps1[r] += __shfl_xor(ps1[r], msk, 64);
        ps2[r] += __shfl_xor(ps2[r], msk, 64);
      }
    }
    if (l15 == 0) {
#pragma unroll
      for (int r = 0; r < 4; r++) {
        s1s[quad * 4 + r][wave] = ps1[r];
        s2s[quad * 4 + r][wave] = ps2[r];
      }
    }
    __syncthreads();
#pragma unroll
    for (int r = 0; r < 4; r++) {
      int row = quad * 4 + r;
      float S1 = 0.f, S2 = 0.f;
#pragma unroll
      for (int w = 0; w < 8; w++) {
        S1 += s1s[row][w];
        S2 += s2s[row][w];
      }
      float mean = S1 * (1.f / HD_SZ);
      float var = S2 * (1.f / HD_SZ) - mean * mean;
      float rs = rsqrtf(var + 1e-5f);
      float wgt = 0.7f * attw[g] + 0.3f * cgr[row][g];
#pragma unroll
      for (int t = 0; t < 3; t++) {
        int d = wave * 48 + t * 16 + l15;
        facc[t * 4 + r] += wgt * ((o[t * 4 + r] - mean) * rs * lng[d] + lnb[d]);
      }
    }
  }
  // write fused bf16 [b][i0+row][d]
#pragma unroll
  for (int r = 0; r < 4; r++) {
    size_t rowo = ((size_t)b * N_SZ + i0 + quad * 4 + r) * HD_SZ;
#pragma unroll
    for (int t = 0; t < 3; t++)
      fusedbf[rowo + wave * 48 + t * 16 + l15] = f2bf(facc[t * 4 + r]);
  }
}

// ---------------------------------------------------------------------------
// LN2 + residual sigmoid gate. One block per (b,n) row. proj bf16, x/out f32.
// ---------------------------------------------------------------------------
__global__ __launch_bounds__(256) void final_kernel(
    const ushort_t* __restrict__ projbf, const float* __restrict__ x,
    const float* __restrict__ ln2g, const float* __restrict__ ln2b,
    float* __restrict__ out) {
  int row = blockIdx.x;
  int tid = threadIdx.x, wave = tid >> 6, lane = tid & 63;
  const ushort_t* pr = projbf + (size_t)row * FD_SZ;
  const float* xr = x + (size_t)row * FD_SZ;
  float v[3], xv[3];
  float s1 = 0.f, s2 = 0.f;
#pragma unroll
  for (int k = 0; k < 3; k++) {
    int c = tid + k * 256;
    v[k] = bf2f(pr[c]);
    xv[k] = xr[c];
    s1 += v[k];
    s2 += v[k] * v[k];
  }
  for (int m = 1; m < 64; m <<= 1) {
    s1 += __shfl_xor(s1, m, 64);
    s2 += __shfl_xor(s2, m, 64);
  }
  __shared__ float rs1[4], rs2[4], rdt[4];
  if (lane == 0) { rs1[wave] = s1; rs2[wave] = s2; }
  __syncthreads();
  s1 = rs1[0] + rs1[1] + rs1[2] + rs1[3];
  s2 = rs2[0] + rs2[1] + rs2[2] + rs2[3];
  float mean = s1 * (1.f / FD_SZ);
  float var = s2 * (1.f / FD_SZ) - mean * mean;
  float rstd = rsqrtf(var + 1e-5f);
  float dot = 0.f;
  float pn[3];
#pragma unroll
  for (int k = 0; k < 3; k++) {
    int c = tid + k * 256;
    pn[k] = (v[k] - mean) * rstd * ln2g[c] + ln2b[c];
    dot += pn[k] * xv[k];
  }
  for (int m = 1; m < 64; m <<= 1) dot += __shfl_xor(dot, m, 64);
  if (lane == 0) rdt[wave] = dot;
  __syncthreads();
  dot = rdt[0] + rdt[1] + rdt[2] + rdt[3];
  float gv = 1.f / (1.f + __expf(-dot * (1.0f / 27.712812921102035f)));  // /sqrt(768)
#pragma unroll
  for (int k = 0; k < 3; k++) {
    int c = tid + k * 256;
    out[(size_t)row * FD_SZ + c] = gv * xv[k] + (1.f - gv) * pn[k];
  }
}

// ---------------------------------------------------------------------------
extern "C" void kernel_launch(void* const* d_in, const int* in_sizes, int n_in,
                              void* d_out, int out_size, void* d_ws, size_t ws_size,
                              hipStream_t stream) {
  (void)in_sizes; (void)n_in; (void)out_size; (void)ws_size;
  const float* x = (const float*)d_in[0];
  const int* adj = (const int*)d_in[1];
  const float* W = (const float*)d_in[2];
  const float* a = (const float*)d_in[3];
  const float* log_unc = (const float*)d_in[4];
  const float* gate_w = (const float*)d_in[5];
  const float* gate_b = (const float*)d_in[6];
  const float* ln1g = (const float*)d_in[7];
  const float* ln1b = (const float*)d_in[8];
  const float* w1 = (const float*)d_in[9];
  const float* b1 = (const float*)d_in[10];
  const float* w2 = (const float*)d_in[11];
  const float* b2 = (const float*)d_in[12];
  const float* ln2g = (const float*)d_in[13];
  const float* ln2b = (const float*)d_in[14];

  // Workspace (peak 53,385,216 B ≈ 50.9 MiB, liveness-overlapped):
  //  [0          ) Wt      1,769,472   (bf16 [G][HD][FD]); after vf GEMM the
  //                 region is dead -> adjm (98,304 B bitmask) reuses offset 0
  //  [1,769,472  ) w1t     294,912
  //  [2,064,384  ) w2t     589,824
  //  [2,654,208  ) cg      6,144
  //  [2,660,352  ) e1      196,608
  //  [2,856,960  ) e2      196,608
  //  [3,053,568  ) fusedbf 12,582,912  (attn -> t1 GEMM)
  //  [15,636,480 ) vf      37,748,736  (tiled V; h GEMM -> attn); reused:
  //  [15,636,480 )   t1bf    12,582,912
  //  [28,219,392 )   projbf  25,165,824
  char* ws = (char*)d_ws;
  ushort_t* Wt      = (ushort_t*)(ws + 0);
  uint_t*   adjm    = (uint_t*)(ws + 0);            // over dead Wt (post-vf)
  ushort_t* w1t     = (ushort_t*)(ws + 1769472);
  ushort_t* w2t     = (ushort_t*)(ws + 2064384);
  float*    cg      = (float*)(ws + 2654208);
  float*    e1      = (float*)(ws + 2660352);
  float*    e2      = (float*)(ws + 2856960);
  ushort_t* fusedbf = (ushort_t*)(ws + 3053568);
  ushort_t* vf      = (ushort_t*)(ws + 15636480);
  ushort_t* t1bf    = (ushort_t*)(ws + 15636480);   // over dead vf
  ushort_t* projbf  = (ushort_t*)(ws + 28219392);   // over dead vf

  transpose_f2b<<<dim3(1152, 1, 3), 256, 0, stream>>>(W, Wt, FD_SZ, HD_SZ);
  transpose_f2b<<<dim3(576, 1, 1), 256, 0, stream>>>(w1, w1t, HD_SZ, HD_SZ);
  transpose_f2b<<<dim3(1152, 1, 1), 256, 0, stream>>>(w2, w2t, HD_SZ, FD_SZ);

  gate_kernel<<<dim3(N_SZ), 256, 0, stream>>>(x, gate_w, gate_b, cg);

  // vf[g] = (x @ W[g]) in V-tile layout, written from the C-fragments
  gemm_kernel<true, false, true, false, true><<<dim3(3, 128, 3), 256, 0, stream>>>(
      x, 0, Wt, (size_t)HD_SZ * FD_SZ, nullptr, vf, 0,
      M_SZ, FD_SZ, HD_SZ);

  // adj -> bitmask, into the now-dead Wt region (must follow the vf GEMM)
  pack_adj<<<dim3((G_SZ * N_SZ * N_SZ) / 256), 256, 0, stream>>>(adj, adjm);

  e12_kernel<<<dim3(M_SZ / 256, G_SZ), 256, 0, stream>>>(vf, a, e1, e2);

  attn_kernel<<<dim3(N_SZ / 16, B_SZ), 512, 0, stream>>>(
      adjm, vf, e1, e2, cg, log_unc, ln1g, ln1b, fusedbf);

  // t1 = relu(fused @ w1 + b1)
  gemm_kernel<false, true, true, true, false><<<dim3(3, 128, 1), 256, 0, stream>>>(
      fusedbf, 0, w1t, 0, b1, t1bf, 0, M_SZ, HD_SZ, HD_SZ);
  // proj = t1 @ w2 + b2 (bf16 out)
  gemm_kernel<false, false, true, true, false><<<dim3(6, 128, 1), 256, 0, stream>>>(
      t1bf, 0, w2t, 0, b2, projbf, 0, M_SZ, HD_SZ, FD_SZ);

  final_kernel<<<dim3(M_SZ), 256, 0, stream>>>(projbf, x, ln2g, ln2b, (float*)d_out);
}

// Round 3
// 348.999 us; speedup vs baseline: 1.1000x; 1.0666x over previous
//
#include <hip/hip_runtime.h>

typedef unsigned short ushort_t;
typedef unsigned int uint_t;
typedef __bf16 bf16x8 __attribute__((ext_vector_type(8)));
typedef float f32x4 __attribute__((ext_vector_type(4)));
typedef unsigned int u32x4 __attribute__((ext_vector_type(4)));
typedef unsigned short u16x4 __attribute__((ext_vector_type(4)));

#define B_SZ 32
#define N_SZ 512
#define FD_SZ 768
#define HD_SZ 384
#define G_SZ 3
#define M_SZ (B_SZ * N_SZ)   // 16384
#define ALPHA_LR 0.2f
#define NEGV -9.0e15f
#define VTILE (HD_SZ * 32)   // elements per (g,b,jt) V-tile: 384 d x 32 j

__device__ __forceinline__ float bf2f(ushort_t u) { return __uint_as_float(((uint_t)u) << 16); }
__device__ __forceinline__ ushort_t f2bf(float f) {
  uint_t x = __float_as_uint(f);
  return (ushort_t)((x + 0x7fffu + ((x >> 16) & 1u)) >> 16);
}
__device__ __forceinline__ u32x4 pack8(f32x4 lo, f32x4 hi) {
  union { ushort_t us[8]; u32x4 v; } pk;
  pk.us[0] = f2bf(lo.x); pk.us[1] = f2bf(lo.y); pk.us[2] = f2bf(lo.z); pk.us[3] = f2bf(lo.w);
  pk.us[4] = f2bf(hi.x); pk.us[5] = f2bf(hi.y); pk.us[6] = f2bf(hi.z); pk.us[7] = f2bf(hi.w);
  return pk.v;
}

// ---------------------------------------------------------------------------
// Transpose + downcast: dst[c*R + r] = bf16(src[r*C + c]), batched over z.
// ---------------------------------------------------------------------------
__global__ __launch_bounds__(256) void transpose_f2b(
    const float* __restrict__ src, ushort_t* __restrict__ dst, int R, int C) {
  size_t total = (size_t)R * C;
  size_t base = (size_t)blockIdx.z * total;
  size_t i = (size_t)blockIdx.x * 256 + threadIdx.x;
  if (i < total) {
    int r = (int)(i / C), c = (int)(i % C);
    dst[base + (size_t)c * R + r] = f2bf(src[base + i]);
  }
}

// ---------------------------------------------------------------------------
// Straight downcast f32 -> bf16, 4 elems/thread (for x; result feeds GEMM A).
// ---------------------------------------------------------------------------
__global__ __launch_bounds__(256) void cast_f2b(
    const float* __restrict__ src, ushort_t* __restrict__ dst) {
  size_t i = (size_t)blockIdx.x * 256 + threadIdx.x;
  f32x4 v = ((const f32x4*)src)[i];
  u16x4 p;
  p[0] = f2bf(v.x); p[1] = f2bf(v.y); p[2] = f2bf(v.z); p[3] = f2bf(v.w);
  ((u16x4*)dst)[i] = p;
}

// ---------------------------------------------------------------------------
// Pack adjacency ints (0/1) into bitmask words: am[i>>5] bit (i&31) = adj[i]!=0
// ---------------------------------------------------------------------------
__global__ __launch_bounds__(256) void pack_adj(
    const int* __restrict__ adj, uint_t* __restrict__ am) {
  size_t i = (size_t)blockIdx.x * 256 + threadIdx.x;
  unsigned long long mask = __ballot(adj[i] != 0);
  int lane = threadIdx.x & 63;
  if ((lane & 31) == 0) am[i >> 5] = (uint_t)(mask >> (lane & 32));
}

// ---------------------------------------------------------------------------
// Content gates: cg[n][g] = softmax_g( mean_b(x[b,n,:]) @ gate_w + gate_b )
// ---------------------------------------------------------------------------
__global__ __launch_bounds__(256) void gate_kernel(
    const float* __restrict__ x, const float* __restrict__ gate_w,
    const float* __restrict__ gate_b, float* __restrict__ cg) {
  int n = blockIdx.x;
  int tid = threadIdx.x;
  float a0 = 0.f, a1 = 0.f, a2 = 0.f;
  for (int f = tid; f < FD_SZ; f += 256) {
    float s = 0.f;
#pragma unroll
    for (int b = 0; b < B_SZ; b++) s += x[((size_t)b * N_SZ + n) * FD_SZ + f];
    float avg = s * (1.0f / B_SZ);
    a0 += avg * gate_w[f * 3 + 0];
    a1 += avg * gate_w[f * 3 + 1];
    a2 += avg * gate_w[f * 3 + 2];
  }
  for (int m = 1; m < 64; m <<= 1) {
    a0 += __shfl_xor(a0, m, 64);
    a1 += __shfl_xor(a1, m, 64);
    a2 += __shfl_xor(a2, m, 64);
  }
  __shared__ float red[3][4];
  int wave = tid >> 6, lane = tid & 63;
  if (lane == 0) { red[0][wave] = a0; red[1][wave] = a1; red[2][wave] = a2; }
  __syncthreads();
  if (tid == 0) {
    float l0 = red[0][0] + red[0][1] + red[0][2] + red[0][3] + gate_b[0];
    float l1 = red[1][0] + red[1][1] + red[1][2] + red[1][3] + gate_b[1];
    float l2 = red[2][0] + red[2][1] + red[2][2] + red[2][3] + gate_b[2];
    float mx = fmaxf(l0, fmaxf(l1, l2));
    float e0 = __expf(l0 - mx), e1 = __expf(l1 - mx), e2 = __expf(l2 - mx);
    float inv = 1.0f / (e0 + e1 + e2);
    cg[n * 3 + 0] = e0 * inv;
    cg[n * 3 + 1] = e1 * inv;
    cg[n * 3 + 2] = e2 * inv;
  }
}

// ---------------------------------------------------------------------------
// MFMA bf16 GEMM: C[M,Nc] = A[M,K] @ B[K,Nc] (+bias, +relu).
// A row-major [M,K]: f32 (downcast in staging) if AF32, else bf16.
// Bt row-major [Nc,K] bf16. 128x128 tile, BK=32, 4 waves 64x64 each.
// VFOUT: write C as V-tiles vf[(z*32+b)*16+jt][d=0..384)[j2=0..32) bf16.
// ---------------------------------------------------------------------------
template <bool AF32, bool RELU, bool OUTBF16, bool HASBIAS, bool VFOUT>
__global__ __launch_bounds__(256) void gemm_kernel(
    const void* __restrict__ Av, size_t strideA,
    const ushort_t* __restrict__ Bt, size_t strideB,
    const float* __restrict__ bias,
    void* __restrict__ Cv, size_t strideC,
    int M, int K, int Nc) {
  __shared__ __attribute__((aligned(16))) ushort_t As[128 * 32];
  __shared__ __attribute__((aligned(16))) ushort_t Bs[128 * 32];
  int tid = threadIdx.x, wave = tid >> 6, lane = tid & 63;
  int m0 = blockIdx.y * 128, n0 = blockIdx.x * 128;
  const float* Abf32 = (const float*)Av + (size_t)blockIdx.z * strideA;
  const ushort_t* Abb16 = (const ushort_t*)Av + (size_t)blockIdx.z * strideA;
  const ushort_t* Bb = Bt + (size_t)blockIdx.z * strideB;

  f32x4 acc[4][4];
  f32x4 z4 = {0.f, 0.f, 0.f, 0.f};
#pragma unroll
  for (int i = 0; i < 4; i++)
#pragma unroll
    for (int j = 0; j < 4; j++) acc[i][j] = z4;

  int wm = (wave & 1) * 64, wn = (wave >> 1) * 64;
  int srow = lane >> 2, schk = (lane & 3) * 8;

  for (int kt = 0; kt < K; kt += 32) {
    u32x4 av[2], bv[2];
#pragma unroll
    for (int i = 0; i < 2; i++) {
      int row = m0 + wave * 32 + i * 16 + srow;
      if (AF32) {
        const float* ap = Abf32 + (size_t)row * K + kt + schk;
        f32x4 lo = *(const f32x4*)ap;
        f32x4 hi = *(const f32x4*)(ap + 4);
        av[i] = pack8(lo, hi);
      } else {
        av[i] = *(const u32x4*)(Abb16 + (size_t)row * K + kt + schk);
      }
      bv[i] = *(const u32x4*)(Bb + (size_t)(n0 + wave * 32 + i * 16 + srow) * K + kt + schk);
    }
    __syncthreads();  // previous tile's frag reads done
#pragma unroll
    for (int i = 0; i < 2; i++) {
      int rowBase = wave * 32 + i * 16;
      *(u32x4*)(As + rowBase * 32 + lane * 8) = av[i];
      *(u32x4*)(Bs + rowBase * 32 + lane * 8) = bv[i];
    }
    __syncthreads();
    bf16x8 af[4], bfr[4];
#pragma unroll
    for (int t = 0; t < 4; t++) {
      af[t] = *(const bf16x8*)(As + (wm + t * 16 + (lane & 15)) * 32 + (lane >> 4) * 8);
      bfr[t] = *(const bf16x8*)(Bs + (wn + t * 16 + (lane & 15)) * 32 + (lane >> 4) * 8);
    }
#pragma unroll
    for (int mt = 0; mt < 4; mt++)
#pragma unroll
      for (int nt = 0; nt < 4; nt++)
        acc[mt][nt] = __builtin_amdgcn_mfma_f32_16x16x32_bf16(af[mt], bfr[nt], acc[mt][nt], 0, 0, 0);
  }

  if (VFOUT) {
#pragma unroll
    for (int mt = 0; mt < 4; mt++) {
#pragma unroll
      for (int nt = 0; nt < 4; nt++) {
        int d = n0 + wn + nt * 16 + (lane & 15);
        int gm = m0 + wm + mt * 16 + (lane >> 4) * 4;
        int b = gm >> 9, jt = (gm >> 5) & 15, j2 = gm & 31;
        u16x4 pk;
#pragma unroll
        for (int r2 = 0; r2 < 4; r2++) pk[r2] = f2bf(acc[mt][nt][r2]);
        size_t off = ((size_t)((blockIdx.z * B_SZ + b) * 16 + jt)) * VTILE + (size_t)d * 32 + j2;
        *(u16x4*)((ushort_t*)Cv + off) = pk;
      }
    }
  } else {
#pragma unroll
    for (int mt = 0; mt < 4; mt++) {
#pragma unroll
      for (int nt = 0; nt < 4; nt++) {
        int gn = n0 + wn + nt * 16 + (lane & 15);
        float bvs = HASBIAS ? bias[gn] : 0.f;
#pragma unroll
        for (int r2 = 0; r2 < 4; r2++) {
          int gm = m0 + wm + mt * 16 + (lane >> 4) * 4 + r2;
          float v = acc[mt][nt][r2] + bvs;
          if (RELU) v = v > 0.f ? v : 0.f;
          size_t off = (size_t)blockIdx.z * strideC + (size_t)gm * Nc + gn;
          if (OUTBF16) ((ushort_t*)Cv)[off] = f2bf(v);
          else ((float*)Cv)[off] = v;
        }
      }
    }
  }
}

// ---------------------------------------------------------------------------
// e1[g,m] = sum_d V[g][m][d]*a1[d];  e2 likewise. V in tiled vf layout.
// ---------------------------------------------------------------------------
__global__ __launch_bounds__(256) void e12_kernel(
    const ushort_t* __restrict__ vf, const float* __restrict__ a,
    float* __restrict__ e1, float* __restrict__ e2) {
  __shared__ float a1s[HD_SZ], a2s[HD_SZ];
  int g = blockIdx.y;
  int tid = threadIdx.x;
  for (int i = tid; i < HD_SZ; i += 256) {
    a1s[i] = a[g * 2 * HD_SZ + i];
    a2s[i] = a[g * 2 * HD_SZ + HD_SZ + i];
  }
  __syncthreads();
  int m = blockIdx.x * 256 + tid;
  int b = m >> 9, jt = (m >> 5) & 15, j2 = m & 31;
  const ushort_t* col = vf + ((size_t)((g * B_SZ + b) * 16 + jt)) * VTILE + j2;
  float s1 = 0.f, s2 = 0.f;
  for (int d = 0; d < HD_SZ; d++) {
    float h = bf2f(col[d * 32]);
    s1 += h * a1s[d];
    s2 += h * a2s[d];
  }
  e1[(size_t)g * M_SZ + m] = s1;
  e2[(size_t)g * M_SZ + m] = s2;
}

// ---------------------------------------------------------------------------
// Attention (MFMA PV) + ELU + LN1 + g-weighted fuse.  QBLK=32.
// One block = (b, 32 query rows), 512 thr / 8 waves. Wave w: softmax rows
// {4w..4w+3}; PV d-slice [w*48, w*48+48) for BOTH 16-row P tiles -> each V
// B-fragment feeds 2 MFMAs (halves V L2 traffic vs QBLK=16: 1.18GB -> 590MB,
// ~34us -> ~17us L2 floor). XCD swizzle pins all 16 i0-blocks of one b to
// (linear%8) so each (g,b) V-tile is served by a single XCD L2 (round-2:
// FETCH 225MB -> 19MB confirmed).
// ---------------------------------------------------------------------------
__global__ __launch_bounds__(512, 4) void attn_kernel(
    const uint_t* __restrict__ adjm, const ushort_t* __restrict__ vf,
    const float* __restrict__ e1, const float* __restrict__ e2,
    const float* __restrict__ cg, const float* __restrict__ log_unc,
    const float* __restrict__ ln1g, const float* __restrict__ ln1b,
    ushort_t* __restrict__ fusedbf) {
  __shared__ __attribute__((aligned(16))) ushort_t Pb[32][520];  // +8 pad
  __shared__ float e2s[512];
  __shared__ float e1r[32];
  __shared__ uint_t amS[32][16];
  __shared__ float lng[HD_SZ], lnb[HD_SZ];
  __shared__ float cgr[32][3];
  __shared__ float s1s[32][8], s2s[32][8];

  int tid = threadIdx.x, wave = tid >> 6, lane = tid & 63;
  int quad = lane >> 4, l15 = lane & 15;
  // XCD-pinning decode (gridDim = (16,32)): same b -> same L%8 -> same XCD
  int L = blockIdx.x + (blockIdx.y << 4);
  int b = (L & 7) + ((L >> 7) << 3);
  int i0 = ((L >> 3) & 15) * 32;

  float iv0 = 1.f / (__expf(log_unc[0]) + 1e-8f);
  float iv1 = 1.f / (__expf(log_unc[1]) + 1e-8f);
  float iv2 = 1.f / (__expf(log_unc[2]) + 1e-8f);
  float mxa = fmaxf(iv0, fmaxf(iv1, iv2));
  float w0 = __expf(iv0 - mxa), w1 = __expf(iv1 - mxa), w2 = __expf(iv2 - mxa);
  float wsum = 1.f / (w0 + w1 + w2);
  float attw[3] = {w0 * wsum, w1 * wsum, w2 * wsum};

  if (tid < HD_SZ) {
    lng[tid] = ln1g[tid];
    lnb[tid] = ln1b[tid];
  }
  if (tid < 96) cgr[tid / 3][tid % 3] = cg[(i0 + tid / 3) * 3 + tid % 3];

  float facc[24];  // [mt][t][r] = mt*12 + t*4 + r
#pragma unroll
  for (int t = 0; t < 24; t++) facc[t] = 0.f;

  for (int g = 0; g < G_SZ; g++) {
    __syncthreads();  // previous iteration's LDS readers done
    if (tid < 32) e1r[tid] = e1[((size_t)g * B_SZ + b) * N_SZ + i0 + tid];
    amS[tid >> 4][tid & 15] = adjm[((size_t)g * N_SZ + i0 + (tid >> 4)) * 16 + (tid & 15)];
    e2s[tid] = e2[((size_t)g * B_SZ + b) * N_SZ + tid];
    __syncthreads();

    // scores + softmax, in-register; wave owns rows {4w .. 4w+3}
#pragma unroll
    for (int rr = 0; rr < 4; rr++) {
      int rw = wave * 4 + rr;
      float e1v = e1r[rw];
      float sv[8];
      float m = -3.0e38f;
#pragma unroll
      for (int jj = 0; jj < 8; jj++) {
        int j = lane + jj * 64;
        float s = e1v + e2s[j];
        s = s > 0.f ? s : ALPHA_LR * s;
        uint_t mw = amS[rw][(lane >> 5) + jj * 2];  // broadcast per half-wave
        s = ((mw >> (j & 31)) & 1u) ? s : NEGV;
        sv[jj] = s;
        m = fmaxf(m, s);
      }
      for (int msk = 1; msk < 64; msk <<= 1) m = fmaxf(m, __shfl_xor(m, msk, 64));
      float sum = 0.f;
#pragma unroll
      for (int jj = 0; jj < 8; jj++) {
        float e = __expf(sv[jj] - m);
        sv[jj] = e;
        sum += e;
      }
      for (int msk = 1; msk < 64; msk <<= 1) sum += __shfl_xor(sum, msk, 64);
      float inv = 1.0f / sum;
#pragma unroll
      for (int jj = 0; jj < 8; jj++) Pb[rw][lane + jj * 64] = f2bf(sv[jj] * inv);
    }
    __syncthreads();

    // PV via MFMA: O[32 x 48-per-wave] = P[32 x 512] @ V; 2 P-tiles share V
    f32x4 acc[2][3];
    f32x4 z4 = {0.f, 0.f, 0.f, 0.f};
#pragma unroll
    for (int mt = 0; mt < 2; mt++)
#pragma unroll
      for (int t = 0; t < 3; t++) acc[mt][t] = z4;
    const ushort_t* vbase = vf + ((size_t)(g * B_SZ + b) * 16) * VTILE;
#pragma unroll 2
    for (int j0 = 0; j0 < N_SZ; j0 += 32) {
      const ushort_t* vtile = vbase + (size_t)(j0 >> 5) * VTILE;
      bf16x8 af0 = *(const bf16x8*)(&Pb[l15][j0 + quad * 8]);
      bf16x8 af1 = *(const bf16x8*)(&Pb[16 + l15][j0 + quad * 8]);
#pragma unroll
      for (int t = 0; t < 3; t++) {
        bf16x8 bf = *(const bf16x8*)(vtile + (wave * 48 + t * 16 + l15) * 32 + quad * 8);
        acc[0][t] = __builtin_amdgcn_mfma_f32_16x16x32_bf16(af0, bf, acc[0][t], 0, 0, 0);
        acc[1][t] = __builtin_amdgcn_mfma_f32_16x16x32_bf16(af1, bf, acc[1][t], 0, 0, 0);
      }
    }

    // epilogue: ELU (in-place in acc), LN stats per row, weight, accumulate
    float ps1[2][4], ps2[2][4];
#pragma unroll
    for (int mt = 0; mt < 2; mt++)
#pragma unroll
      for (int r = 0; r < 4; r++) { ps1[mt][r] = 0.f; ps2[mt][r] = 0.f; }
#pragma unroll
    for (int mt = 0; mt < 2; mt++)
#pragma unroll
      for (int t = 0; t < 3; t++)
#pragma unroll
        for (int r = 0; r < 4; r++) {
          float v = acc[mt][t][r];
          v = v > 0.f ? v : __expf(v) - 1.f;
          acc[mt][t][r] = v;
          ps1[mt][r] += v;
          ps2[mt][r] += v * v;
        }
#pragma unroll
    for (int msk = 1; msk < 16; msk <<= 1) {
#pragma unroll
      for (int mt = 0; mt < 2; mt++)
#pragma unroll
        for (int r = 0; r < 4; r++) {
          ps1[mt][r] += __shfl_xor(ps1[mt][r], msk, 64);
          ps2[mt][r] += __shfl_xor(ps2[mt][r], msk, 64);
        }
    }
    if (l15 == 0) {
#pragma unroll
      for (int mt = 0; mt < 2; mt++)
#pragma unroll
        for (int r = 0; r < 4; r++) {
          s1s[mt * 16 + quad * 4 + r][wave] = ps1[mt][r];
          s2s[mt * 16 + quad * 4 + r][wave] = ps2[mt][r];
        }
    }
    __syncthreads();
#pragma unroll
    for (int mt = 0; mt < 2; mt++)
#pragma unroll
      for (int r = 0; r < 4; r++) {
        int row = mt * 16 + quad * 4 + r;
        float S1 = 0.f, S2 = 0.f;
#pragma unroll
        for (int w = 0; w < 8; w++) {
          S1 += s1s[row][w];
          S2 += s2s[row][w];
        }
        float mean = S1 * (1.f / HD_SZ);
        float var = S2 * (1.f / HD_SZ) - mean * mean;
        float rs = rsqrtf(var + 1e-5f);
        float wgt = 0.7f * attw[g] + 0.3f * cgr[row][g];
#pragma unroll
        for (int t = 0; t < 3; t++) {
          int d = wave * 48 + t * 16 + l15;
          facc[mt * 12 + t * 4 + r] += wgt * ((acc[mt][t][r] - mean) * rs * lng[d] + lnb[d]);
        }
      }
  }
  // write fused bf16 [b][i0+row][d]
#pragma unroll
  for (int mt = 0; mt < 2; mt++)
#pragma unroll
    for (int r = 0; r < 4; r++) {
      size_t rowo = ((size_t)b * N_SZ + i0 + mt * 16 + quad * 4 + r) * HD_SZ;
#pragma unroll
      for (int t = 0; t < 3; t++)
        fusedbf[rowo + wave * 48 + t * 16 + l15] = f2bf(facc[mt * 12 + t * 4 + r]);
    }
}

// ---------------------------------------------------------------------------
// LN2 + residual sigmoid gate. One block per (b,n) row. proj bf16, x/out f32.
// ---------------------------------------------------------------------------
__global__ __launch_bounds__(256) void final_kernel(
    const ushort_t* __restrict__ projbf, const float* __restrict__ x,
    const float* __restrict__ ln2g, const float* __restrict__ ln2b,
    float* __restrict__ out) {
  int row = blockIdx.x;
  int tid = threadIdx.x, wave = tid >> 6, lane = tid & 63;
  const ushort_t* pr = projbf + (size_t)row * FD_SZ;
  const float* xr = x + (size_t)row * FD_SZ;
  float v[3], xv[3];
  float s1 = 0.f, s2 = 0.f;
#pragma unroll
  for (int k = 0; k < 3; k++) {
    int c = tid + k * 256;
    v[k] = bf2f(pr[c]);
    xv[k] = xr[c];
    s1 += v[k];
    s2 += v[k] * v[k];
  }
  for (int m = 1; m < 64; m <<= 1) {
    s1 += __shfl_xor(s1, m, 64);
    s2 += __shfl_xor(s2, m, 64);
  }
  __shared__ float rs1[4], rs2[4], rdt[4];
  if (lane == 0) { rs1[wave] = s1; rs2[wave] = s2; }
  __syncthreads();
  s1 = rs1[0] + rs1[1] + rs1[2] + rs1[3];
  s2 = rs2[0] + rs2[1] + rs2[2] + rs2[3];
  float mean = s1 * (1.f / FD_SZ);
  float var = s2 * (1.f / FD_SZ) - mean * mean;
  float rstd = rsqrtf(var + 1e-5f);
  float dot = 0.f;
  float pn[3];
#pragma unroll
  for (int k = 0; k < 3; k++) {
    int c = tid + k * 256;
    pn[k] = (v[k] - mean) * rstd * ln2g[c] + ln2b[c];
    dot += pn[k] * xv[k];
  }
  for (int m = 1; m < 64; m <<= 1) dot += __shfl_xor(dot, m, 64);
  if (lane == 0) rdt[wave] = dot;
  __syncthreads();
  dot = rdt[0] + rdt[1] + rdt[2] + rdt[3];
  float gv = 1.f / (1.f + __expf(-dot * (1.0f / 27.712812921102035f)));  // /sqrt(768)
#pragma unroll
  for (int k = 0; k < 3; k++) {
    int c = tid + k * 256;
    out[(size_t)row * FD_SZ + c] = gv * xv[k] + (1.f - gv) * pn[k];
  }
}

// ---------------------------------------------------------------------------
extern "C" void kernel_launch(void* const* d_in, const int* in_sizes, int n_in,
                              void* d_out, int out_size, void* d_ws, size_t ws_size,
                              hipStream_t stream) {
  (void)in_sizes; (void)n_in; (void)out_size; (void)ws_size;
  const float* x = (const float*)d_in[0];
  const int* adj = (const int*)d_in[1];
  const float* W = (const float*)d_in[2];
  const float* a = (const float*)d_in[3];
  const float* log_unc = (const float*)d_in[4];
  const float* gate_w = (const float*)d_in[5];
  const float* gate_b = (const float*)d_in[6];
  const float* ln1g = (const float*)d_in[7];
  const float* ln1b = (const float*)d_in[8];
  const float* w1 = (const float*)d_in[9];
  const float* b1 = (const float*)d_in[10];
  const float* w2 = (const float*)d_in[11];
  const float* b2 = (const float*)d_in[12];
  const float* ln2g = (const float*)d_in[13];
  const float* ln2b = (const float*)d_in[14];

  // Workspace (peak 53,385,216 B ≈ 50.9 MiB, liveness-overlapped):
  //  [0          ) Wt      1,769,472   -> adjm (96 KB) after vf GEMM
  //  [1,769,472  ) w1t     294,912
  //  [2,064,384  ) w2t     589,824
  //  [2,654,208  ) cg      6,144
  //  [2,660,352  ) e1      196,608
  //  [2,856,960  ) e2      196,608
  //  [3,053,568  ) fusedbf 12,582,912
  //  [15,636,480 ) vf      37,748,736 ; reused: t1bf / projbf
  // xb (bf16 x, 25,165,824 B) lives in d_out (50.3 MB, dead until final).
  char* ws = (char*)d_ws;
  ushort_t* Wt      = (ushort_t*)(ws + 0);
  uint_t*   adjm    = (uint_t*)(ws + 0);            // over dead Wt (post-vf)
  ushort_t* w1t     = (ushort_t*)(ws + 1769472);
  ushort_t* w2t     = (ushort_t*)(ws + 2064384);
  float*    cg      = (float*)(ws + 2654208);
  float*    e1      = (float*)(ws + 2660352);
  float*    e2      = (float*)(ws + 2856960);
  ushort_t* fusedbf = (ushort_t*)(ws + 3053568);
  ushort_t* vf      = (ushort_t*)(ws + 15636480);
  ushort_t* t1bf    = (ushort_t*)(ws + 15636480);   // over dead vf
  ushort_t* projbf  = (ushort_t*)(ws + 28219392);   // over dead vf
  ushort_t* xb      = (ushort_t*)d_out;             // scratch until final

  cast_f2b<<<dim3((M_SZ * FD_SZ) / 1024), 256, 0, stream>>>(x, xb);

  transpose_f2b<<<dim3(1152, 1, 3), 256, 0, stream>>>(W, Wt, FD_SZ, HD_SZ);
  transpose_f2b<<<dim3(576, 1, 1), 256, 0, stream>>>(w1, w1t, HD_SZ, HD_SZ);
  transpose_f2b<<<dim3(1152, 1, 1), 256, 0, stream>>>(w2, w2t, HD_SZ, FD_SZ);

  gate_kernel<<<dim3(N_SZ), 256, 0, stream>>>(x, gate_w, gate_b, cg);

  // vf[g] = (x @ W[g]) in V-tile layout; A = bf16 precast (halves A traffic)
  gemm_kernel<false, false, true, false, true><<<dim3(3, 128, 3), 256, 0, stream>>>(
      xb, 0, Wt, (size_t)HD_SZ * FD_SZ, nullptr, vf, 0,
      M_SZ, FD_SZ, HD_SZ);

  // adj -> bitmask, into the now-dead Wt region (must follow the vf GEMM)
  pack_adj<<<dim3((G_SZ * N_SZ * N_SZ) / 256), 256, 0, stream>>>(adj, adjm);

  e12_kernel<<<dim3(M_SZ / 256, G_SZ), 256, 0, stream>>>(vf, a, e1, e2);

  attn_kernel<<<dim3(N_SZ / 32, B_SZ), 512, 0, stream>>>(
      adjm, vf, e1, e2, cg, log_unc, ln1g, ln1b, fusedbf);

  // t1 = relu(fused @ w1 + b1)
  gemm_kernel<false, true, true, true, false><<<dim3(3, 128, 1), 256, 0, stream>>>(
      fusedbf, 0, w1t, 0, b1, t1bf, 0, M_SZ, HD_SZ, HD_SZ);
  // proj = t1 @ w2 + b2 (bf16 out)
  gemm_kernel<false, false, true, true, false><<<dim3(6, 128, 1), 256, 0, stream>>>(
      t1bf, 0, w2t, 0, b2, projbf, 0, M_SZ, HD_SZ, FD_SZ);

  final_kernel<<<dim3(M_SZ), 256, 0, stream>>>(projbf, x, ln2g, ln2b, (float*)d_out);
}

// Round 4
// 341.169 us; speedup vs baseline: 1.1252x; 1.0230x over previous
//
#include <hip/hip_runtime.h>

typedef unsigned short ushort_t;
typedef unsigned int uint_t;
typedef __bf16 bf16x8 __attribute__((ext_vector_type(8)));
typedef float f32x4 __attribute__((ext_vector_type(4)));
typedef unsigned int u32x4 __attribute__((ext_vector_type(4)));
typedef unsigned short u16x4 __attribute__((ext_vector_type(4)));
typedef unsigned short u16x8 __attribute__((ext_vector_type(8)));

#define B_SZ 32
#define N_SZ 512
#define FD_SZ 768
#define HD_SZ 384
#define G_SZ 3
#define M_SZ (B_SZ * N_SZ)   // 16384
#define ALPHA_LR 0.2f
#define NEGV -9.0e15f
#define VTILE (HD_SZ * 32)   // elements per (g,b,jt) V-tile: 384 d x 32 j
#define PSLICE ((size_t)M_SZ * HD_SZ)  // elems per g-slice of partials

__device__ __forceinline__ float bf2f(ushort_t u) { return __uint_as_float(((uint_t)u) << 16); }
__device__ __forceinline__ ushort_t f2bf(float f) {
  uint_t x = __float_as_uint(f);
  return (ushort_t)((x + 0x7fffu + ((x >> 16) & 1u)) >> 16);
}
__device__ __forceinline__ u32x4 pack8(f32x4 lo, f32x4 hi) {
  union { ushort_t us[8]; u32x4 v; } pk;
  pk.us[0] = f2bf(lo.x); pk.us[1] = f2bf(lo.y); pk.us[2] = f2bf(lo.z); pk.us[3] = f2bf(lo.w);
  pk.us[4] = f2bf(hi.x); pk.us[5] = f2bf(hi.y); pk.us[6] = f2bf(hi.z); pk.us[7] = f2bf(hi.w);
  return pk.v;
}

// ---------------------------------------------------------------------------
// Transpose + downcast: dst[c*R + r] = bf16(src[r*C + c]), batched over z.
// ---------------------------------------------------------------------------
__global__ __launch_bounds__(256) void transpose_f2b(
    const float* __restrict__ src, ushort_t* __restrict__ dst, int R, int C) {
  size_t total = (size_t)R * C;
  size_t base = (size_t)blockIdx.z * total;
  size_t i = (size_t)blockIdx.x * 256 + threadIdx.x;
  if (i < total) {
    int r = (int)(i / C), c = (int)(i % C);
    dst[base + (size_t)c * R + r] = f2bf(src[base + i]);
  }
}

// ---------------------------------------------------------------------------
// Straight downcast f32 -> bf16, 4 elems/thread (for x; result feeds GEMM A).
// ---------------------------------------------------------------------------
__global__ __launch_bounds__(256) void cast_f2b(
    const float* __restrict__ src, ushort_t* __restrict__ dst) {
  size_t i = (size_t)blockIdx.x * 256 + threadIdx.x;
  f32x4 v = ((const f32x4*)src)[i];
  u16x4 p;
  p[0] = f2bf(v.x); p[1] = f2bf(v.y); p[2] = f2bf(v.z); p[3] = f2bf(v.w);
  ((u16x4*)dst)[i] = p;
}

// ---------------------------------------------------------------------------
// Pack adjacency ints (0/1) into bitmask words: am[i>>5] bit (i&31) = adj[i]!=0
// ---------------------------------------------------------------------------
__global__ __launch_bounds__(256) void pack_adj(
    const int* __restrict__ adj, uint_t* __restrict__ am) {
  size_t i = (size_t)blockIdx.x * 256 + threadIdx.x;
  unsigned long long mask = __ballot(adj[i] != 0);
  int lane = threadIdx.x & 63;
  if ((lane & 31) == 0) am[i >> 5] = (uint_t)(mask >> (lane & 32));
}

// ---------------------------------------------------------------------------
// Content gates: cg[n][g] = softmax_g( mean_b(x[b,n,:]) @ gate_w + gate_b )
// ---------------------------------------------------------------------------
__global__ __launch_bounds__(256) void gate_kernel(
    const float* __restrict__ x, const float* __restrict__ gate_w,
    const float* __restrict__ gate_b, float* __restrict__ cg) {
  int n = blockIdx.x;
  int tid = threadIdx.x;
  float a0 = 0.f, a1 = 0.f, a2 = 0.f;
  for (int f = tid; f < FD_SZ; f += 256) {
    float s = 0.f;
#pragma unroll
    for (int b = 0; b < B_SZ; b++) s += x[((size_t)b * N_SZ + n) * FD_SZ + f];
    float avg = s * (1.0f / B_SZ);
    a0 += avg * gate_w[f * 3 + 0];
    a1 += avg * gate_w[f * 3 + 1];
    a2 += avg * gate_w[f * 3 + 2];
  }
  for (int m = 1; m < 64; m <<= 1) {
    a0 += __shfl_xor(a0, m, 64);
    a1 += __shfl_xor(a1, m, 64);
    a2 += __shfl_xor(a2, m, 64);
  }
  __shared__ float red[3][4];
  int wave = tid >> 6, lane = tid & 63;
  if (lane == 0) { red[0][wave] = a0; red[1][wave] = a1; red[2][wave] = a2; }
  __syncthreads();
  if (tid == 0) {
    float l0 = red[0][0] + red[0][1] + red[0][2] + red[0][3] + gate_b[0];
    float l1 = red[1][0] + red[1][1] + red[1][2] + red[1][3] + gate_b[1];
    float l2 = red[2][0] + red[2][1] + red[2][2] + red[2][3] + gate_b[2];
    float mx = fmaxf(l0, fmaxf(l1, l2));
    float e0 = __expf(l0 - mx), e1 = __expf(l1 - mx), e2 = __expf(l2 - mx);
    float inv = 1.0f / (e0 + e1 + e2);
    cg[n * 3 + 0] = e0 * inv;
    cg[n * 3 + 1] = e1 * inv;
    cg[n * 3 + 2] = e2 * inv;
  }
}

// ---------------------------------------------------------------------------
// MFMA bf16 GEMM: C[M,Nc] = A[M,K] @ B[K,Nc] (+bias, +relu).
// A row-major [M,K]: f32 (downcast in staging) if AF32, else bf16.
// Bt row-major [Nc,K] bf16. 128x128 tile, BK=32, 4 waves 64x64 each.
// VFOUT: write C as V-tiles vf[(z*32+b)*16+jt][d=0..384)[j2=0..32) bf16.
// ---------------------------------------------------------------------------
template <bool AF32, bool RELU, bool OUTBF16, bool HASBIAS, bool VFOUT>
__global__ __launch_bounds__(256) void gemm_kernel(
    const void* __restrict__ Av, size_t strideA,
    const ushort_t* __restrict__ Bt, size_t strideB,
    const float* __restrict__ bias,
    void* __restrict__ Cv, size_t strideC,
    int M, int K, int Nc) {
  __shared__ __attribute__((aligned(16))) ushort_t As[128 * 32];
  __shared__ __attribute__((aligned(16))) ushort_t Bs[128 * 32];
  int tid = threadIdx.x, wave = tid >> 6, lane = tid & 63;
  int m0 = blockIdx.y * 128, n0 = blockIdx.x * 128;
  const float* Abf32 = (const float*)Av + (size_t)blockIdx.z * strideA;
  const ushort_t* Abb16 = (const ushort_t*)Av + (size_t)blockIdx.z * strideA;
  const ushort_t* Bb = Bt + (size_t)blockIdx.z * strideB;

  f32x4 acc[4][4];
  f32x4 z4 = {0.f, 0.f, 0.f, 0.f};
#pragma unroll
  for (int i = 0; i < 4; i++)
#pragma unroll
    for (int j = 0; j < 4; j++) acc[i][j] = z4;

  int wm = (wave & 1) * 64, wn = (wave >> 1) * 64;
  int srow = lane >> 2, schk = (lane & 3) * 8;

  for (int kt = 0; kt < K; kt += 32) {
    u32x4 av[2], bv[2];
#pragma unroll
    for (int i = 0; i < 2; i++) {
      int row = m0 + wave * 32 + i * 16 + srow;
      if (AF32) {
        const float* ap = Abf32 + (size_t)row * K + kt + schk;
        f32x4 lo = *(const f32x4*)ap;
        f32x4 hi = *(const f32x4*)(ap + 4);
        av[i] = pack8(lo, hi);
      } else {
        av[i] = *(const u32x4*)(Abb16 + (size_t)row * K + kt + schk);
      }
      bv[i] = *(const u32x4*)(Bb + (size_t)(n0 + wave * 32 + i * 16 + srow) * K + kt + schk);
    }
    __syncthreads();  // previous tile's frag reads done
#pragma unroll
    for (int i = 0; i < 2; i++) {
      int rowBase = wave * 32 + i * 16;
      *(u32x4*)(As + rowBase * 32 + lane * 8) = av[i];
      *(u32x4*)(Bs + rowBase * 32 + lane * 8) = bv[i];
    }
    __syncthreads();
    bf16x8 af[4], bfr[4];
#pragma unroll
    for (int t = 0; t < 4; t++) {
      af[t] = *(const bf16x8*)(As + (wm + t * 16 + (lane & 15)) * 32 + (lane >> 4) * 8);
      bfr[t] = *(const bf16x8*)(Bs + (wn + t * 16 + (lane & 15)) * 32 + (lane >> 4) * 8);
    }
#pragma unroll
    for (int mt = 0; mt < 4; mt++)
#pragma unroll
      for (int nt = 0; nt < 4; nt++)
        acc[mt][nt] = __builtin_amdgcn_mfma_f32_16x16x32_bf16(af[mt], bfr[nt], acc[mt][nt], 0, 0, 0);
  }

  if (VFOUT) {
#pragma unroll
    for (int mt = 0; mt < 4; mt++) {
#pragma unroll
      for (int nt = 0; nt < 4; nt++) {
        int d = n0 + wn + nt * 16 + (lane & 15);
        int gm = m0 + wm + mt * 16 + (lane >> 4) * 4;
        int b = gm >> 9, jt = (gm >> 5) & 15, j2 = gm & 31;
        u16x4 pk;
#pragma unroll
        for (int r2 = 0; r2 < 4; r2++) pk[r2] = f2bf(acc[mt][nt][r2]);
        size_t off = ((size_t)((blockIdx.z * B_SZ + b) * 16 + jt)) * VTILE + (size_t)d * 32 + j2;
        *(u16x4*)((ushort_t*)Cv + off) = pk;
      }
    }
  } else {
#pragma unroll
    for (int mt = 0; mt < 4; mt++) {
#pragma unroll
      for (int nt = 0; nt < 4; nt++) {
        int gn = n0 + wn + nt * 16 + (lane & 15);
        float bvs = HASBIAS ? bias[gn] : 0.f;
#pragma unroll
        for (int r2 = 0; r2 < 4; r2++) {
          int gm = m0 + wm + mt * 16 + (lane >> 4) * 4 + r2;
          float v = acc[mt][nt][r2] + bvs;
          if (RELU) v = v > 0.f ? v : 0.f;
          size_t off = (size_t)blockIdx.z * strideC + (size_t)gm * Nc + gn;
          if (OUTBF16) ((ushort_t*)Cv)[off] = f2bf(v);
          else ((float*)Cv)[off] = v;
        }
      }
    }
  }
}

// ---------------------------------------------------------------------------
// e1[g,m] = sum_d V[g][m][d]*a1[d];  e2 likewise. V in tiled vf layout.
// ---------------------------------------------------------------------------
__global__ __launch_bounds__(256) void e12_kernel(
    const ushort_t* __restrict__ vf, const float* __restrict__ a,
    float* __restrict__ e1, float* __restrict__ e2) {
  __shared__ float a1s[HD_SZ], a2s[HD_SZ];
  int g = blockIdx.y;
  int tid = threadIdx.x;
  for (int i = tid; i < HD_SZ; i += 256) {
    a1s[i] = a[g * 2 * HD_SZ + i];
    a2s[i] = a[g * 2 * HD_SZ + HD_SZ + i];
  }
  __syncthreads();
  int m = blockIdx.x * 256 + tid;
  int b = m >> 9, jt = (m >> 5) & 15, j2 = m & 31;
  const ushort_t* col = vf + ((size_t)((g * B_SZ + b) * 16 + jt)) * VTILE + j2;
  float s1 = 0.f, s2 = 0.f;
  for (int d = 0; d < HD_SZ; d++) {
    float h = bf2f(col[d * 32]);
    s1 += h * a1s[d];
    s2 += h * a2s[d];
  }
  e1[(size_t)g * M_SZ + m] = s1;
  e2[(size_t)g * M_SZ + m] = s2;
}

// ---------------------------------------------------------------------------
// Attention (MFMA PV) + ELU + LN1 + g-weight.  QBLK=32, SPLIT-G.
// Grid (16, 32, 3): block = (i0-tile, b, g). Round-3 was grid-limited (512
// blocks = 2/CU, occupancy 39%); the g-loop is independent until the fuse
// sum, so split it: 1536 blocks = 6/CU offered, 3 resident (43KB LDS), and
// each block's serial chain is 1/3 length. Block writes its g's contribution
// wgt*LN(ELU(PV)) as bf16 partials pf[g][m][d] (in d_out scratch); reduce3
// sums the slices. XCD swizzle unchanged: same b -> same L%8 -> same XCD L2
// (z-slices are 512 blocks apart, 512%8==0, mapping preserved per g).
// ---------------------------------------------------------------------------
__global__ __launch_bounds__(512, 4) void attn_kernel(
    const uint_t* __restrict__ adjm, const ushort_t* __restrict__ vf,
    const float* __restrict__ e1, const float* __restrict__ e2,
    const float* __restrict__ cg, const float* __restrict__ log_unc,
    const float* __restrict__ ln1g, const float* __restrict__ ln1b,
    ushort_t* __restrict__ pf) {
  __shared__ __attribute__((aligned(16))) ushort_t Pb[32][520];  // +8 pad
  __shared__ float e2s[512];
  __shared__ float e1r[32];
  __shared__ uint_t amS[32][16];
  __shared__ float lng[HD_SZ], lnb[HD_SZ];
  __shared__ float cgr[32];     // cg for own g only
  __shared__ float s1s[32][8], s2s[32][8];

  int tid = threadIdx.x, wave = tid >> 6, lane = tid & 63;
  int quad = lane >> 4, l15 = lane & 15;
  int g = blockIdx.z;
  // XCD-pinning decode (gridDim = (16,32,3)): same b -> same L%8 -> same XCD
  int L = blockIdx.x + (blockIdx.y << 4);
  int b = (L & 7) + ((L >> 7) << 3);
  int i0 = ((L >> 3) & 15) * 32;

  float iv0 = 1.f / (__expf(log_unc[0]) + 1e-8f);
  float iv1 = 1.f / (__expf(log_unc[1]) + 1e-8f);
  float iv2 = 1.f / (__expf(log_unc[2]) + 1e-8f);
  float mxa = fmaxf(iv0, fmaxf(iv1, iv2));
  float w0 = __expf(iv0 - mxa), w1 = __expf(iv1 - mxa), w2 = __expf(iv2 - mxa);
  float wsum = 1.f / (w0 + w1 + w2);
  float attwg = (g == 0 ? w0 : (g == 1 ? w1 : w2)) * wsum;

  if (tid < HD_SZ) {
    lng[tid] = ln1g[tid];
    lnb[tid] = ln1b[tid];
  }
  if (tid < 32) {
    cgr[tid] = cg[(i0 + tid) * 3 + g];
    e1r[tid] = e1[((size_t)g * B_SZ + b) * N_SZ + i0 + tid];
  }
  amS[tid >> 4][tid & 15] = adjm[((size_t)g * N_SZ + i0 + (tid >> 4)) * 16 + (tid & 15)];
  e2s[tid] = e2[((size_t)g * B_SZ + b) * N_SZ + tid];
  __syncthreads();

  // scores + softmax, in-register; wave owns rows {4w .. 4w+3}
#pragma unroll
  for (int rr = 0; rr < 4; rr++) {
    int rw = wave * 4 + rr;
    float e1v = e1r[rw];
    float sv[8];
    float m = -3.0e38f;
#pragma unroll
    for (int jj = 0; jj < 8; jj++) {
      int j = lane + jj * 64;
      float s = e1v + e2s[j];
      s = s > 0.f ? s : ALPHA_LR * s;
      uint_t mw = amS[rw][(lane >> 5) + jj * 2];  // broadcast per half-wave
      s = ((mw >> (j & 31)) & 1u) ? s : NEGV;
      sv[jj] = s;
      m = fmaxf(m, s);
    }
    for (int msk = 1; msk < 64; msk <<= 1) m = fmaxf(m, __shfl_xor(m, msk, 64));
    float sum = 0.f;
#pragma unroll
    for (int jj = 0; jj < 8; jj++) {
      float e = __expf(sv[jj] - m);
      sv[jj] = e;
      sum += e;
    }
    for (int msk = 1; msk < 64; msk <<= 1) sum += __shfl_xor(sum, msk, 64);
    float inv = 1.0f / sum;
#pragma unroll
    for (int jj = 0; jj < 8; jj++) Pb[rw][lane + jj * 64] = f2bf(sv[jj] * inv);
  }
  __syncthreads();

  // PV via MFMA: O[32 x 48-per-wave] = P[32 x 512] @ V; 2 P-tiles share V
  f32x4 acc[2][3];
  f32x4 z4 = {0.f, 0.f, 0.f, 0.f};
#pragma unroll
  for (int mt = 0; mt < 2; mt++)
#pragma unroll
    for (int t = 0; t < 3; t++) acc[mt][t] = z4;
  const ushort_t* vbase = vf + ((size_t)(g * B_SZ + b) * 16) * VTILE;
#pragma unroll 2
  for (int j0 = 0; j0 < N_SZ; j0 += 32) {
    const ushort_t* vtile = vbase + (size_t)(j0 >> 5) * VTILE;
    bf16x8 af0 = *(const bf16x8*)(&Pb[l15][j0 + quad * 8]);
    bf16x8 af1 = *(const bf16x8*)(&Pb[16 + l15][j0 + quad * 8]);
#pragma unroll
    for (int t = 0; t < 3; t++) {
      bf16x8 bf = *(const bf16x8*)(vtile + (wave * 48 + t * 16 + l15) * 32 + quad * 8);
      acc[0][t] = __builtin_amdgcn_mfma_f32_16x16x32_bf16(af0, bf, acc[0][t], 0, 0, 0);
      acc[1][t] = __builtin_amdgcn_mfma_f32_16x16x32_bf16(af1, bf, acc[1][t], 0, 0, 0);
    }
  }

  // epilogue: ELU (in-place in acc), LN stats per row, weight, write partial
  float ps1[2][4], ps2[2][4];
#pragma unroll
  for (int mt = 0; mt < 2; mt++)
#pragma unroll
    for (int r = 0; r < 4; r++) { ps1[mt][r] = 0.f; ps2[mt][r] = 0.f; }
#pragma unroll
  for (int mt = 0; mt < 2; mt++)
#pragma unroll
    for (int t = 0; t < 3; t++)
#pragma unroll
      for (int r = 0; r < 4; r++) {
        float v = acc[mt][t][r];
        v = v > 0.f ? v : __expf(v) - 1.f;
        acc[mt][t][r] = v;
        ps1[mt][r] += v;
        ps2[mt][r] += v * v;
      }
#pragma unroll
  for (int msk = 1; msk < 16; msk <<= 1) {
#pragma unroll
    for (int mt = 0; mt < 2; mt++)
#pragma unroll
      for (int r = 0; r < 4; r++) {
        ps1[mt][r] += __shfl_xor(ps1[mt][r], msk, 64);
        ps2[mt][r] += __shfl_xor(ps2[mt][r], msk, 64);
      }
  }
  if (l15 == 0) {
#pragma unroll
    for (int mt = 0; mt < 2; mt++)
#pragma unroll
      for (int r = 0; r < 4; r++) {
        s1s[mt * 16 + quad * 4 + r][wave] = ps1[mt][r];
        s2s[mt * 16 + quad * 4 + r][wave] = ps2[mt][r];
      }
  }
  __syncthreads();
#pragma unroll
  for (int mt = 0; mt < 2; mt++)
#pragma unroll
    for (int r = 0; r < 4; r++) {
      int row = mt * 16 + quad * 4 + r;
      float S1 = 0.f, S2 = 0.f;
#pragma unroll
      for (int w = 0; w < 8; w++) {
        S1 += s1s[row][w];
        S2 += s2s[row][w];
      }
      float mean = S1 * (1.f / HD_SZ);
      float var = S2 * (1.f / HD_SZ) - mean * mean;
      float rs = rsqrtf(var + 1e-5f);
      float wgt = 0.7f * attwg + 0.3f * cgr[row];
      size_t rowo = (size_t)g * PSLICE + ((size_t)b * N_SZ + i0 + row) * HD_SZ;
#pragma unroll
      for (int t = 0; t < 3; t++) {
        int d = wave * 48 + t * 16 + l15;
        pf[rowo + d] = f2bf(wgt * ((acc[mt][t][r] - mean) * rs * lng[d] + lnb[d]));
      }
    }
}

// ---------------------------------------------------------------------------
// fused[m*HD+d] = bf16( sum_g pf[g][m*HD+d] ).  8 bf16 per thread (16B I/O).
// ---------------------------------------------------------------------------
__global__ __launch_bounds__(256) void reduce3_kernel(
    const ushort_t* __restrict__ pf, ushort_t* __restrict__ fused) {
  size_t u = ((size_t)blockIdx.x * 256 + threadIdx.x) * 8;
  u16x8 a = *(const u16x8*)(pf + u);
  u16x8 b = *(const u16x8*)(pf + PSLICE + u);
  u16x8 c = *(const u16x8*)(pf + 2 * PSLICE + u);
  u16x8 o;
#pragma unroll
  for (int k = 0; k < 8; k++)
    o[k] = f2bf(bf2f(a[k]) + bf2f(b[k]) + bf2f(c[k]));
  *(u16x8*)(fused + u) = o;
}

// ---------------------------------------------------------------------------
// LN2 + residual sigmoid gate. One block per (b,n) row. proj bf16, x/out f32.
// ---------------------------------------------------------------------------
__global__ __launch_bounds__(256) void final_kernel(
    const ushort_t* __restrict__ projbf, const float* __restrict__ x,
    const float* __restrict__ ln2g, const float* __restrict__ ln2b,
    float* __restrict__ out) {
  int row = blockIdx.x;
  int tid = threadIdx.x, wave = tid >> 6, lane = tid & 63;
  const ushort_t* pr = projbf + (size_t)row * FD_SZ;
  const float* xr = x + (size_t)row * FD_SZ;
  float v[3], xv[3];
  float s1 = 0.f, s2 = 0.f;
#pragma unroll
  for (int k = 0; k < 3; k++) {
    int c = tid + k * 256;
    v[k] = bf2f(pr[c]);
    xv[k] = xr[c];
    s1 += v[k];
    s2 += v[k] * v[k];
  }
  for (int m = 1; m < 64; m <<= 1) {
    s1 += __shfl_xor(s1, m, 64);
    s2 += __shfl_xor(s2, m, 64);
  }
  __shared__ float rs1[4], rs2[4], rdt[4];
  if (lane == 0) { rs1[wave] = s1; rs2[wave] = s2; }
  __syncthreads();
  s1 = rs1[0] + rs1[1] + rs1[2] + rs1[3];
  s2 = rs2[0] + rs2[1] + rs2[2] + rs2[3];
  float mean = s1 * (1.f / FD_SZ);
  float var = s2 * (1.f / FD_SZ) - mean * mean;
  float rstd = rsqrtf(var + 1e-5f);
  float dot = 0.f;
  float pn[3];
#pragma unroll
  for (int k = 0; k < 3; k++) {
    int c = tid + k * 256;
    pn[k] = (v[k] - mean) * rstd * ln2g[c] + ln2b[c];
    dot += pn[k] * xv[k];
  }
  for (int m = 1; m < 64; m <<= 1) dot += __shfl_xor(dot, m, 64);
  if (lane == 0) rdt[wave] = dot;
  __syncthreads();
  dot = rdt[0] + rdt[1] + rdt[2] + rdt[3];
  float gv = 1.f / (1.f + __expf(-dot * (1.0f / 27.712812921102035f)));  // /sqrt(768)
#pragma unroll
  for (int k = 0; k < 3; k++) {
    int c = tid + k * 256;
    out[(size_t)row * FD_SZ + c] = gv * xv[k] + (1.f - gv) * pn[k];
  }
}

// ---------------------------------------------------------------------------
extern "C" void kernel_launch(void* const* d_in, const int* in_sizes, int n_in,
                              void* d_out, int out_size, void* d_ws, size_t ws_size,
                              hipStream_t stream) {
  (void)in_sizes; (void)n_in; (void)out_size; (void)ws_size;
  const float* x = (const float*)d_in[0];
  const int* adj = (const int*)d_in[1];
  const float* W = (const float*)d_in[2];
  const float* a = (const float*)d_in[3];
  const float* log_unc = (const float*)d_in[4];
  const float* gate_w = (const float*)d_in[5];
  const float* gate_b = (const float*)d_in[6];
  const float* ln1g = (const float*)d_in[7];
  const float* ln1b = (const float*)d_in[8];
  const float* w1 = (const float*)d_in[9];
  const float* b1 = (const float*)d_in[10];
  const float* w2 = (const float*)d_in[11];
  const float* b2 = (const float*)d_in[12];
  const float* ln2g = (const float*)d_in[13];
  const float* ln2b = (const float*)d_in[14];

  // Workspace (peak 53,385,216 B ≈ 50.9 MiB, liveness-overlapped):
  //  [0          ) Wt      1,769,472   -> adjm (96 KB) after vf GEMM
  //  [1,769,472  ) w1t     294,912
  //  [2,064,384  ) w2t     589,824
  //  [2,654,208  ) cg      6,144
  //  [2,660,352  ) e1      196,608
  //  [2,856,960  ) e2      196,608
  //  [3,053,568  ) fusedbf 12,582,912
  //  [15,636,480 ) vf      37,748,736 ; reused: t1bf / projbf
  // d_out (50.3 MB) triple-duty scratch: xb (bf16 x, 25.2 MB, live until vf
  // GEMM) -> pf (bf16 g-partials, 37.7 MB, attn -> reduce3) -> final output.
  char* ws = (char*)d_ws;
  ushort_t* Wt      = (ushort_t*)(ws + 0);
  uint_t*   adjm    = (uint_t*)(ws + 0);            // over dead Wt (post-vf)
  ushort_t* w1t     = (ushort_t*)(ws + 1769472);
  ushort_t* w2t     = (ushort_t*)(ws + 2064384);
  float*    cg      = (float*)(ws + 2654208);
  float*    e1      = (float*)(ws + 2660352);
  float*    e2      = (float*)(ws + 2856960);
  ushort_t* fusedbf = (ushort_t*)(ws + 3053568);
  ushort_t* vf      = (ushort_t*)(ws + 15636480);
  ushort_t* t1bf    = (ushort_t*)(ws + 15636480);   // over dead vf
  ushort_t* projbf  = (ushort_t*)(ws + 28219392);   // over dead vf
  ushort_t* xb      = (ushort_t*)d_out;             // scratch until vf GEMM
  ushort_t* pf      = (ushort_t*)d_out;             // scratch: attn partials

  cast_f2b<<<dim3((M_SZ * FD_SZ) / 1024), 256, 0, stream>>>(x, xb);

  transpose_f2b<<<dim3(1152, 1, 3), 256, 0, stream>>>(W, Wt, FD_SZ, HD_SZ);
  transpose_f2b<<<dim3(576, 1, 1), 256, 0, stream>>>(w1, w1t, HD_SZ, HD_SZ);
  transpose_f2b<<<dim3(1152, 1, 1), 256, 0, stream>>>(w2, w2t, HD_SZ, FD_SZ);

  gate_kernel<<<dim3(N_SZ), 256, 0, stream>>>(x, gate_w, gate_b, cg);

  // vf[g] = (x @ W[g]) in V-tile layout; A = bf16 precast
  gemm_kernel<false, false, true, false, true><<<dim3(3, 128, 3), 256, 0, stream>>>(
      xb, 0, Wt, (size_t)HD_SZ * FD_SZ, nullptr, vf, 0,
      M_SZ, FD_SZ, HD_SZ);

  // adj -> bitmask, into the now-dead Wt region (must follow the vf GEMM)
  pack_adj<<<dim3((G_SZ * N_SZ * N_SZ) / 256), 256, 0, stream>>>(adj, adjm);

  e12_kernel<<<dim3(M_SZ / 256, G_SZ), 256, 0, stream>>>(vf, a, e1, e2);

  // split-g attention -> bf16 partials in d_out (xb dead after vf GEMM)
  attn_kernel<<<dim3(N_SZ / 32, B_SZ, G_SZ), 512, 0, stream>>>(
      adjm, vf, e1, e2, cg, log_unc, ln1g, ln1b, pf);

  reduce3_kernel<<<dim3((M_SZ * HD_SZ) / (256 * 8)), 256, 0, stream>>>(pf, fusedbf);

  // t1 = relu(fused @ w1 + b1)
  gemm_kernel<false, true, true, true, false><<<dim3(3, 128, 1), 256, 0, stream>>>(
      fusedbf, 0, w1t, 0, b1, t1bf, 0, M_SZ, HD_SZ, HD_SZ);
  // proj = t1 @ w2 + b2 (bf16 out)
  gemm_kernel<false, false, true, true, false><<<dim3(6, 128, 1), 256, 0, stream>>>(
      t1bf, 0, w2t, 0, b2, projbf, 0, M_SZ, HD_SZ, FD_SZ);

  final_kernel<<<dim3(M_SZ), 256, 0, stream>>>(projbf, x, ln2g, ln2b, (float*)d_out);
}

// Round 5
// 335.876 us; speedup vs baseline: 1.1429x; 1.0158x over previous
//
#include <hip/hip_runtime.h>

typedef unsigned short ushort_t;
typedef unsigned int uint_t;
typedef __bf16 bf16x8 __attribute__((ext_vector_type(8)));
typedef float f32x4 __attribute__((ext_vector_type(4)));
typedef unsigned int u32x4 __attribute__((ext_vector_type(4)));
typedef unsigned short u16x4 __attribute__((ext_vector_type(4)));
typedef unsigned short u16x8 __attribute__((ext_vector_type(8)));

#define B_SZ 32
#define N_SZ 512
#define FD_SZ 768
#define HD_SZ 384
#define G_SZ 3
#define M_SZ (B_SZ * N_SZ)   // 16384
#define ALPHA_LR 0.2f
#define NEGV -9.0e15f
#define VTILE (HD_SZ * 32)   // elements per (g,b,jt) V-tile: 384 d x 32 j
#define PSLICE ((size_t)M_SZ * HD_SZ)  // elems per g-slice of partials

__device__ __forceinline__ float bf2f(ushort_t u) { return __uint_as_float(((uint_t)u) << 16); }
__device__ __forceinline__ ushort_t f2bf(float f) {
  uint_t x = __float_as_uint(f);
  return (ushort_t)((x + 0x7fffu + ((x >> 16) & 1u)) >> 16);
}

// Async global->LDS, 16B per lane. LDS dest is wave-uniform base + lane*16
// (linear); global src is per-lane. Compiler-inserted vmcnt(0) before the
// following s_barrier makes the data visible after __syncthreads().
__device__ __forceinline__ void gload_lds16(const ushort_t* g, ushort_t* l) {
  __builtin_amdgcn_global_load_lds(
      (const __attribute__((address_space(1))) uint_t*)(const void*)g,
      (__attribute__((address_space(3))) uint_t*)(void*)l, 16, 0, 0);
}

// ---------------------------------------------------------------------------
// Transpose + downcast: dst[c*R + r] = bf16(src[r*C + c]), batched over z.
// ---------------------------------------------------------------------------
__global__ __launch_bounds__(256) void transpose_f2b(
    const float* __restrict__ src, ushort_t* __restrict__ dst, int R, int C) {
  size_t total = (size_t)R * C;
  size_t base = (size_t)blockIdx.z * total;
  size_t i = (size_t)blockIdx.x * 256 + threadIdx.x;
  if (i < total) {
    int r = (int)(i / C), c = (int)(i % C);
    dst[base + (size_t)c * R + r] = f2bf(src[base + i]);
  }
}

// ---------------------------------------------------------------------------
// Straight downcast f32 -> bf16, 4 elems/thread (for x; result feeds GEMM A).
// ---------------------------------------------------------------------------
__global__ __launch_bounds__(256) void cast_f2b(
    const float* __restrict__ src, ushort_t* __restrict__ dst) {
  size_t i = (size_t)blockIdx.x * 256 + threadIdx.x;
  f32x4 v = ((const f32x4*)src)[i];
  u16x4 p;
  p[0] = f2bf(v.x); p[1] = f2bf(v.y); p[2] = f2bf(v.z); p[3] = f2bf(v.w);
  ((u16x4*)dst)[i] = p;
}

// ---------------------------------------------------------------------------
// Pack adjacency ints (0/1) into bitmask words: am[i>>5] bit (i&31) = adj[i]!=0
// ---------------------------------------------------------------------------
__global__ __launch_bounds__(256) void pack_adj(
    const int* __restrict__ adj, uint_t* __restrict__ am) {
  size_t i = (size_t)blockIdx.x * 256 + threadIdx.x;
  unsigned long long mask = __ballot(adj[i] != 0);
  int lane = threadIdx.x & 63;
  if ((lane & 31) == 0) am[i >> 5] = (uint_t)(mask >> (lane & 32));
}

// ---------------------------------------------------------------------------
// Content gates: cg[n][g] = softmax_g( mean_b(x[b,n,:]) @ gate_w + gate_b )
// ---------------------------------------------------------------------------
__global__ __launch_bounds__(256) void gate_kernel(
    const float* __restrict__ x, const float* __restrict__ gate_w,
    const float* __restrict__ gate_b, float* __restrict__ cg) {
  int n = blockIdx.x;
  int tid = threadIdx.x;
  float a0 = 0.f, a1 = 0.f, a2 = 0.f;
  for (int f = tid; f < FD_SZ; f += 256) {
    float s = 0.f;
#pragma unroll
    for (int b = 0; b < B_SZ; b++) s += x[((size_t)b * N_SZ + n) * FD_SZ + f];
    float avg = s * (1.0f / B_SZ);
    a0 += avg * gate_w[f * 3 + 0];
    a1 += avg * gate_w[f * 3 + 1];
    a2 += avg * gate_w[f * 3 + 2];
  }
  for (int m = 1; m < 64; m <<= 1) {
    a0 += __shfl_xor(a0, m, 64);
    a1 += __shfl_xor(a1, m, 64);
    a2 += __shfl_xor(a2, m, 64);
  }
  __shared__ float red[3][4];
  int wave = tid >> 6, lane = tid & 63;
  if (lane == 0) { red[0][wave] = a0; red[1][wave] = a1; red[2][wave] = a2; }
  __syncthreads();
  if (tid == 0) {
    float l0 = red[0][0] + red[0][1] + red[0][2] + red[0][3] + gate_b[0];
    float l1 = red[1][0] + red[1][1] + red[1][2] + red[1][3] + gate_b[1];
    float l2 = red[2][0] + red[2][1] + red[2][2] + red[2][3] + gate_b[2];
    float mx = fmaxf(l0, fmaxf(l1, l2));
    float e0 = __expf(l0 - mx), e1 = __expf(l1 - mx), e2 = __expf(l2 - mx);
    float inv = 1.0f / (e0 + e1 + e2);
    cg[n * 3 + 0] = e0 * inv;
    cg[n * 3 + 1] = e1 * inv;
    cg[n * 3 + 2] = e2 * inv;
  }
}

// ---------------------------------------------------------------------------
// MFMA bf16 GEMM: C[M,Nc] = A[M,K] @ B[K,Nc] (+bias, +relu). All inputs bf16.
// Bt row-major [Nc,K]. 128x128 tile, BK=32, 4 waves 64x64 each.
// Staging via global_load_lds width=16 (m97 pattern: +67% over reg-staging;
// compiler never auto-emits it). LDS layout linear row*64B + lane*16B ==
// wave-uniform base + lane*16 as the instruction requires.
// VFOUT: write C as V-tiles vf[(z*32+b)*16+jt][d=0..384)[j2=0..32) bf16.
// ---------------------------------------------------------------------------
template <bool RELU, bool OUTBF16, bool HASBIAS, bool VFOUT>
__global__ __launch_bounds__(256) void gemm_kernel(
    const ushort_t* __restrict__ Ab, size_t strideA,
    const ushort_t* __restrict__ Bt, size_t strideB,
    const float* __restrict__ bias,
    void* __restrict__ Cv, size_t strideC,
    int M, int K, int Nc) {
  __shared__ __attribute__((aligned(16))) ushort_t As[128 * 32];
  __shared__ __attribute__((aligned(16))) ushort_t Bs[128 * 32];
  int tid = threadIdx.x, wave = tid >> 6, lane = tid & 63;
  int m0 = blockIdx.y * 128, n0 = blockIdx.x * 128;
  const ushort_t* A = Ab + (size_t)blockIdx.z * strideA;
  const ushort_t* Bb = Bt + (size_t)blockIdx.z * strideB;

  f32x4 acc[4][4];
  f32x4 z4 = {0.f, 0.f, 0.f, 0.f};
#pragma unroll
  for (int i = 0; i < 4; i++)
#pragma unroll
    for (int j = 0; j < 4; j++) acc[i][j] = z4;

  int wm = (wave & 1) * 64, wn = (wave >> 1) * 64;
  int srow = lane >> 2, schk = (lane & 3) * 8;

  for (int kt = 0; kt < K; kt += 32) {
    __syncthreads();  // previous tile's frag reads done (kt=0: harmless)
#pragma unroll
    for (int i = 0; i < 2; i++) {
      int rowBase = wave * 32 + i * 16;
      gload_lds16(A + (size_t)(m0 + rowBase + srow) * K + kt + schk,
                  As + rowBase * 32);
      gload_lds16(Bb + (size_t)(n0 + rowBase + srow) * K + kt + schk,
                  Bs + rowBase * 32);
    }
    __syncthreads();  // vmcnt(0) drained before barrier -> tiles visible
    bf16x8 af[4], bfr[4];
#pragma unroll
    for (int t = 0; t < 4; t++) {
      af[t] = *(const bf16x8*)(As + (wm + t * 16 + (lane & 15)) * 32 + (lane >> 4) * 8);
      bfr[t] = *(const bf16x8*)(Bs + (wn + t * 16 + (lane & 15)) * 32 + (lane >> 4) * 8);
    }
#pragma unroll
    for (int mt = 0; mt < 4; mt++)
#pragma unroll
      for (int nt = 0; nt < 4; nt++)
        acc[mt][nt] = __builtin_amdgcn_mfma_f32_16x16x32_bf16(af[mt], bfr[nt], acc[mt][nt], 0, 0, 0);
  }

  if (VFOUT) {
#pragma unroll
    for (int mt = 0; mt < 4; mt++) {
#pragma unroll
      for (int nt = 0; nt < 4; nt++) {
        int d = n0 + wn + nt * 16 + (lane & 15);
        int gm = m0 + wm + mt * 16 + (lane >> 4) * 4;
        int b = gm >> 9, jt = (gm >> 5) & 15, j2 = gm & 31;
        u16x4 pk;
#pragma unroll
        for (int r2 = 0; r2 < 4; r2++) pk[r2] = f2bf(acc[mt][nt][r2]);
        size_t off = ((size_t)((blockIdx.z * B_SZ + b) * 16 + jt)) * VTILE + (size_t)d * 32 + j2;
        *(u16x4*)((ushort_t*)Cv + off) = pk;
      }
    }
  } else {
#pragma unroll
    for (int mt = 0; mt < 4; mt++) {
#pragma unroll
      for (int nt = 0; nt < 4; nt++) {
        int gn = n0 + wn + nt * 16 + (lane & 15);
        float bvs = HASBIAS ? bias[gn] : 0.f;
#pragma unroll
        for (int r2 = 0; r2 < 4; r2++) {
          int gm = m0 + wm + mt * 16 + (lane >> 4) * 4 + r2;
          float v = acc[mt][nt][r2] + bvs;
          if (RELU) v = v > 0.f ? v : 0.f;
          size_t off = (size_t)blockIdx.z * strideC + (size_t)gm * Nc + gn;
          if (OUTBF16) ((ushort_t*)Cv)[off] = f2bf(v);
          else ((float*)Cv)[off] = v;
        }
      }
    }
  }
}

// ---------------------------------------------------------------------------
// e1[g,m] = sum_d V[g][m][d]*a1[d];  e2 likewise. V in tiled vf layout.
// 4 lanes per m (each 96 d) + 4-way shfl reduce: grid (M/64, 3) = 768 blocks
// (was 192 = 0.75/CU, latency-bound on a 384-deep serial chain).
// ---------------------------------------------------------------------------
__global__ __launch_bounds__(256) void e12_kernel(
    const ushort_t* __restrict__ vf, const float* __restrict__ a,
    float* __restrict__ e1, float* __restrict__ e2) {
  __shared__ float a1s[HD_SZ], a2s[HD_SZ];
  int g = blockIdx.y;
  int tid = threadIdx.x;
  for (int i = tid; i < HD_SZ; i += 256) {
    a1s[i] = a[g * 2 * HD_SZ + i];
    a2s[i] = a[g * 2 * HD_SZ + HD_SZ + i];
  }
  __syncthreads();
  int m = blockIdx.x * 64 + (tid >> 2), dq = tid & 3;
  int b = m >> 9, jt = (m >> 5) & 15, j2 = m & 31;
  const ushort_t* col = vf + ((size_t)((g * B_SZ + b) * 16 + jt)) * VTILE + j2;
  float s1 = 0.f, s2 = 0.f;
#pragma unroll 4
  for (int k = 0; k < 96; k++) {
    int d = dq * 96 + k;
    float h = bf2f(col[d * 32]);
    s1 += h * a1s[d];
    s2 += h * a2s[d];
  }
  s1 += __shfl_xor(s1, 1, 64); s1 += __shfl_xor(s1, 2, 64);
  s2 += __shfl_xor(s2, 1, 64); s2 += __shfl_xor(s2, 2, 64);
  if (dq == 0) {
    e1[(size_t)g * M_SZ + m] = s1;
    e2[(size_t)g * M_SZ + m] = s2;
  }
}

// ---------------------------------------------------------------------------
// Attention (MFMA PV) + ELU + LN1 + g-weight.  QBLK=32, SPLIT-G.
// Grid (16, 32, 3): block = (i0-tile, b, g). Partials pf[g][m][d] in d_out.
// XCD swizzle: same b -> same L%8 -> same XCD L2 for the (g,b) V-tile.
// ---------------------------------------------------------------------------
__global__ __launch_bounds__(512, 4) void attn_kernel(
    const uint_t* __restrict__ adjm, const ushort_t* __restrict__ vf,
    const float* __restrict__ e1, const float* __restrict__ e2,
    const float* __restrict__ cg, const float* __restrict__ log_unc,
    const float* __restrict__ ln1g, const float* __restrict__ ln1b,
    ushort_t* __restrict__ pf) {
  __shared__ __attribute__((aligned(16))) ushort_t Pb[32][520];  // +8 pad
  __shared__ float e2s[512];
  __shared__ float e1r[32];
  __shared__ uint_t amS[32][16];
  __shared__ float lng[HD_SZ], lnb[HD_SZ];
  __shared__ float cgr[32];     // cg for own g only
  __shared__ float s1s[32][8], s2s[32][8];

  int tid = threadIdx.x, wave = tid >> 6, lane = tid & 63;
  int quad = lane >> 4, l15 = lane & 15;
  int g = blockIdx.z;
  int L = blockIdx.x + (blockIdx.y << 4);
  int b = (L & 7) + ((L >> 7) << 3);
  int i0 = ((L >> 3) & 15) * 32;

  float iv0 = 1.f / (__expf(log_unc[0]) + 1e-8f);
  float iv1 = 1.f / (__expf(log_unc[1]) + 1e-8f);
  float iv2 = 1.f / (__expf(log_unc[2]) + 1e-8f);
  float mxa = fmaxf(iv0, fmaxf(iv1, iv2));
  float w0 = __expf(iv0 - mxa), w1 = __expf(iv1 - mxa), w2 = __expf(iv2 - mxa);
  float wsum = 1.f / (w0 + w1 + w2);
  float attwg = (g == 0 ? w0 : (g == 1 ? w1 : w2)) * wsum;

  if (tid < HD_SZ) {
    lng[tid] = ln1g[tid];
    lnb[tid] = ln1b[tid];
  }
  if (tid < 32) {
    cgr[tid] = cg[(i0 + tid) * 3 + g];
    e1r[tid] = e1[((size_t)g * B_SZ + b) * N_SZ + i0 + tid];
  }
  amS[tid >> 4][tid & 15] = adjm[((size_t)g * N_SZ + i0 + (tid >> 4)) * 16 + (tid & 15)];
  e2s[tid] = e2[((size_t)g * B_SZ + b) * N_SZ + tid];
  __syncthreads();

  // scores + softmax, in-register; wave owns rows {4w .. 4w+3}
#pragma unroll
  for (int rr = 0; rr < 4; rr++) {
    int rw = wave * 4 + rr;
    float e1v = e1r[rw];
    float sv[8];
    float m = -3.0e38f;
#pragma unroll
    for (int jj = 0; jj < 8; jj++) {
      int j = lane + jj * 64;
      float s = e1v + e2s[j];
      s = s > 0.f ? s : ALPHA_LR * s;
      uint_t mw = amS[rw][(lane >> 5) + jj * 2];  // broadcast per half-wave
      s = ((mw >> (j & 31)) & 1u) ? s : NEGV;
      sv[jj] = s;
      m = fmaxf(m, s);
    }
    for (int msk = 1; msk < 64; msk <<= 1) m = fmaxf(m, __shfl_xor(m, msk, 64));
    float sum = 0.f;
#pragma unroll
    for (int jj = 0; jj < 8; jj++) {
      float e = __expf(sv[jj] - m);
      sv[jj] = e;
      sum += e;
    }
    for (int msk = 1; msk < 64; msk <<= 1) sum += __shfl_xor(sum, msk, 64);
    float inv = 1.0f / sum;
#pragma unroll
    for (int jj = 0; jj < 8; jj++) Pb[rw][lane + jj * 64] = f2bf(sv[jj] * inv);
  }
  __syncthreads();

  // PV via MFMA: O[32 x 48-per-wave] = P[32 x 512] @ V; 2 P-tiles share V
  f32x4 acc[2][3];
  f32x4 z4 = {0.f, 0.f, 0.f, 0.f};
#pragma unroll
  for (int mt = 0; mt < 2; mt++)
#pragma unroll
    for (int t = 0; t < 3; t++) acc[mt][t] = z4;
  const ushort_t* vbase = vf + ((size_t)(g * B_SZ + b) * 16) * VTILE;
  __builtin_amdgcn_s_setprio(1);
#pragma unroll 2
  for (int j0 = 0; j0 < N_SZ; j0 += 32) {
    const ushort_t* vtile = vbase + (size_t)(j0 >> 5) * VTILE;
    bf16x8 af0 = *(const bf16x8*)(&Pb[l15][j0 + quad * 8]);
    bf16x8 af1 = *(const bf16x8*)(&Pb[16 + l15][j0 + quad * 8]);
#pragma unroll
    for (int t = 0; t < 3; t++) {
      bf16x8 bf = *(const bf16x8*)(vtile + (wave * 48 + t * 16 + l15) * 32 + quad * 8);
      acc[0][t] = __builtin_amdgcn_mfma_f32_16x16x32_bf16(af0, bf, acc[0][t], 0, 0, 0);
      acc[1][t] = __builtin_amdgcn_mfma_f32_16x16x32_bf16(af1, bf, acc[1][t], 0, 0, 0);
    }
  }
  __builtin_amdgcn_s_setprio(0);

  // epilogue: ELU (in-place in acc), LN stats per row, weight, write partial
  float ps1[2][4], ps2[2][4];
#pragma unroll
  for (int mt = 0; mt < 2; mt++)
#pragma unroll
    for (int r = 0; r < 4; r++) { ps1[mt][r] = 0.f; ps2[mt][r] = 0.f; }
#pragma unroll
  for (int mt = 0; mt < 2; mt++)
#pragma unroll
    for (int t = 0; t < 3; t++)
#pragma unroll
      for (int r = 0; r < 4; r++) {
        float v = acc[mt][t][r];
        v = v > 0.f ? v : __expf(v) - 1.f;
        acc[mt][t][r] = v;
        ps1[mt][r] += v;
        ps2[mt][r] += v * v;
      }
#pragma unroll
  for (int msk = 1; msk < 16; msk <<= 1) {
#pragma unroll
    for (int mt = 0; mt < 2; mt++)
#pragma unroll
      for (int r = 0; r < 4; r++) {
        ps1[mt][r] += __shfl_xor(ps1[mt][r], msk, 64);
        ps2[mt][r] += __shfl_xor(ps2[mt][r], msk, 64);
      }
  }
  if (l15 == 0) {
#pragma unroll
    for (int mt = 0; mt < 2; mt++)
#pragma unroll
      for (int r = 0; r < 4; r++) {
        s1s[mt * 16 + quad * 4 + r][wave] = ps1[mt][r];
        s2s[mt * 16 + quad * 4 + r][wave] = ps2[mt][r];
      }
  }
  __syncthreads();
#pragma unroll
  for (int mt = 0; mt < 2; mt++)
#pragma unroll
    for (int r = 0; r < 4; r++) {
      int row = mt * 16 + quad * 4 + r;
      float S1 = 0.f, S2 = 0.f;
#pragma unroll
      for (int w = 0; w < 8; w++) {
        S1 += s1s[row][w];
        S2 += s2s[row][w];
      }
      float mean = S1 * (1.f / HD_SZ);
      float var = S2 * (1.f / HD_SZ) - mean * mean;
      float rs = rsqrtf(var + 1e-5f);
      float wgt = 0.7f * attwg + 0.3f * cgr[row];
      size_t rowo = (size_t)g * PSLICE + ((size_t)b * N_SZ + i0 + row) * HD_SZ;
#pragma unroll
      for (int t = 0; t < 3; t++) {
        int d = wave * 48 + t * 16 + l15;
        pf[rowo + d] = f2bf(wgt * ((acc[mt][t][r] - mean) * rs * lng[d] + lnb[d]));
      }
    }
}

// ---------------------------------------------------------------------------
// fused[m*HD+d] = bf16( sum_g pf[g][m*HD+d] ).  8 bf16 per thread (16B I/O).
// ---------------------------------------------------------------------------
__global__ __launch_bounds__(256) void reduce3_kernel(
    const ushort_t* __restrict__ pf, ushort_t* __restrict__ fused) {
  size_t u = ((size_t)blockIdx.x * 256 + threadIdx.x) * 8;
  u16x8 a = *(const u16x8*)(pf + u);
  u16x8 b = *(const u16x8*)(pf + PSLICE + u);
  u16x8 c = *(const u16x8*)(pf + 2 * PSLICE + u);
  u16x8 o;
#pragma unroll
  for (int k = 0; k < 8; k++)
    o[k] = f2bf(bf2f(a[k]) + bf2f(b[k]) + bf2f(c[k]));
  *(u16x8*)(fused + u) = o;
}

// ---------------------------------------------------------------------------
// LN2 + residual sigmoid gate. One block per (b,n) row. proj bf16, x/out f32.
// ---------------------------------------------------------------------------
__global__ __launch_bounds__(256) void final_kernel(
    const ushort_t* __restrict__ projbf, const float* __restrict__ x,
    const float* __restrict__ ln2g, const float* __restrict__ ln2b,
    float* __restrict__ out) {
  int row = blockIdx.x;
  int tid = threadIdx.x, wave = tid >> 6, lane = tid & 63;
  const ushort_t* pr = projbf + (size_t)row * FD_SZ;
  const float* xr = x + (size_t)row * FD_SZ;
  float v[3], xv[3];
  float s1 = 0.f, s2 = 0.f;
#pragma unroll
  for (int k = 0; k < 3; k++) {
    int c = tid + k * 256;
    v[k] = bf2f(pr[c]);
    xv[k] = xr[c];
    s1 += v[k];
    s2 += v[k] * v[k];
  }
  for (int m = 1; m < 64; m <<= 1) {
    s1 += __shfl_xor(s1, m, 64);
    s2 += __shfl_xor(s2, m, 64);
  }
  __shared__ float rs1[4], rs2[4], rdt[4];
  if (lane == 0) { rs1[wave] = s1; rs2[wave] = s2; }
  __syncthreads();
  s1 = rs1[0] + rs1[1] + rs1[2] + rs1[3];
  s2 = rs2[0] + rs2[1] + rs2[2] + rs2[3];
  float mean = s1 * (1.f / FD_SZ);
  float var = s2 * (1.f / FD_SZ) - mean * mean;
  float rstd = rsqrtf(var + 1e-5f);
  float dot = 0.f;
  float pn[3];
#pragma unroll
  for (int k = 0; k < 3; k++) {
    int c = tid + k * 256;
    pn[k] = (v[k] - mean) * rstd * ln2g[c] + ln2b[c];
    dot += pn[k] * xv[k];
  }
  for (int m = 1; m < 64; m <<= 1) dot += __shfl_xor(dot, m, 64);
  if (lane == 0) rdt[wave] = dot;
  __syncthreads();
  dot = rdt[0] + rdt[1] + rdt[2] + rdt[3];
  float gv = 1.f / (1.f + __expf(-dot * (1.0f / 27.712812921102035f)));  // /sqrt(768)
#pragma unroll
  for (int k = 0; k < 3; k++) {
    int c = tid + k * 256;
    out[(size_t)row * FD_SZ + c] = gv * xv[k] + (1.f - gv) * pn[k];
  }
}

// ---------------------------------------------------------------------------
extern "C" void kernel_launch(void* const* d_in, const int* in_sizes, int n_in,
                              void* d_out, int out_size, void* d_ws, size_t ws_size,
                              hipStream_t stream) {
  (void)in_sizes; (void)n_in; (void)out_size; (void)ws_size;
  const float* x = (const float*)d_in[0];
  const int* adj = (const int*)d_in[1];
  const float* W = (const float*)d_in[2];
  const float* a = (const float*)d_in[3];
  const float* log_unc = (const float*)d_in[4];
  const float* gate_w = (const float*)d_in[5];
  const float* gate_b = (const float*)d_in[6];
  const float* ln1g = (const float*)d_in[7];
  const float* ln1b = (const float*)d_in[8];
  const float* w1 = (const float*)d_in[9];
  const float* b1 = (const float*)d_in[10];
  const float* w2 = (const float*)d_in[11];
  const float* b2 = (const float*)d_in[12];
  const float* ln2g = (const float*)d_in[13];
  const float* ln2b = (const float*)d_in[14];

  // Workspace (peak 53,385,216 B ≈ 50.9 MiB, liveness-overlapped):
  //  [0          ) Wt      1,769,472   -> adjm (96 KB) after vf GEMM
  //  [1,769,472  ) w1t     294,912
  //  [2,064,384  ) w2t     589,824
  //  [2,654,208  ) cg      6,144
  //  [2,660,352  ) e1      196,608
  //  [2,856,960  ) e2      196,608
  //  [3,053,568  ) fusedbf 12,582,912
  //  [15,636,480 ) vf      37,748,736 ; reused: t1bf / projbf
  // d_out (50.3 MB) triple-duty scratch: xb (bf16 x, 25.2 MB, live until vf
  // GEMM) -> pf (bf16 g-partials, 37.7 MB, attn -> reduce3) -> final output.
  char* ws = (char*)d_ws;
  ushort_t* Wt      = (ushort_t*)(ws + 0);
  uint_t*   adjm    = (uint_t*)(ws + 0);            // over dead Wt (post-vf)
  ushort_t* w1t     = (ushort_t*)(ws + 1769472);
  ushort_t* w2t     = (ushort_t*)(ws + 2064384);
  float*    cg      = (float*)(ws + 2654208);
  float*    e1      = (float*)(ws + 2660352);
  float*    e2      = (float*)(ws + 2856960);
  ushort_t* fusedbf = (ushort_t*)(ws + 3053568);
  ushort_t* vf      = (ushort_t*)(ws + 15636480);
  ushort_t* t1bf    = (ushort_t*)(ws + 15636480);   // over dead vf
  ushort_t* projbf  = (ushort_t*)(ws + 28219392);   // over dead vf
  ushort_t* xb      = (ushort_t*)d_out;             // scratch until vf GEMM
  ushort_t* pf      = (ushort_t*)d_out;             // scratch: attn partials

  cast_f2b<<<dim3((M_SZ * FD_SZ) / 1024), 256, 0, stream>>>(x, xb);

  transpose_f2b<<<dim3(1152, 1, 3), 256, 0, stream>>>(W, Wt, FD_SZ, HD_SZ);
  transpose_f2b<<<dim3(576, 1, 1), 256, 0, stream>>>(w1, w1t, HD_SZ, HD_SZ);
  transpose_f2b<<<dim3(1152, 1, 1), 256, 0, stream>>>(w2, w2t, HD_SZ, FD_SZ);

  gate_kernel<<<dim3(N_SZ), 256, 0, stream>>>(x, gate_w, gate_b, cg);

  // vf[g] = (x @ W[g]) in V-tile layout; A = bf16 precast
  gemm_kernel<false, true, false, true><<<dim3(3, 128, 3), 256, 0, stream>>>(
      xb, 0, Wt, (size_t)HD_SZ * FD_SZ, nullptr, vf, 0,
      M_SZ, FD_SZ, HD_SZ);

  // adj -> bitmask, into the now-dead Wt region (must follow the vf GEMM)
  pack_adj<<<dim3((G_SZ * N_SZ * N_SZ) / 256), 256, 0, stream>>>(adj, adjm);

  e12_kernel<<<dim3(M_SZ / 64, G_SZ), 256, 0, stream>>>(vf, a, e1, e2);

  // split-g attention -> bf16 partials in d_out (xb dead after vf GEMM)
  attn_kernel<<<dim3(N_SZ / 32, B_SZ, G_SZ), 512, 0, stream>>>(
      adjm, vf, e1, e2, cg, log_unc, ln1g, ln1b, pf);

  reduce3_kernel<<<dim3((M_SZ * HD_SZ) / (256 * 8)), 256, 0, stream>>>(pf, fusedbf);

  // t1 = relu(fused @ w1 + b1)
  gemm_kernel<true, true, true, false><<<dim3(3, 128, 1), 256, 0, stream>>>(
      fusedbf, 0, w1t, 0, b1, t1bf, 0, M_SZ, HD_SZ, HD_SZ);
  // proj = t1 @ w2 + b2 (bf16 out)
  gemm_kernel<false, true, true, false><<<dim3(6, 128, 1), 256, 0, stream>>>(
      t1bf, 0, w2t, 0, b2, projbf, 0, M_SZ, HD_SZ, FD_SZ);

  final_kernel<<<dim3(M_SZ), 256, 0, stream>>>(projbf, x, ln2g, ln2b, (float*)d_out);
}

// Round 6
// 327.628 us; speedup vs baseline: 1.1717x; 1.0252x over previous
//
#include <hip/hip_runtime.h>

typedef unsigned short ushort_t;
typedef unsigned int uint_t;
typedef __bf16 bf16x8 __attribute__((ext_vector_type(8)));
typedef float f32x4 __attribute__((ext_vector_type(4)));
typedef unsigned int u32x4 __attribute__((ext_vector_type(4)));
typedef unsigned short u16x4 __attribute__((ext_vector_type(4)));
typedef unsigned short u16x8 __attribute__((ext_vector_type(8)));

#define B_SZ 32
#define N_SZ 512
#define FD_SZ 768
#define HD_SZ 384
#define G_SZ 3
#define M_SZ (B_SZ * N_SZ)   // 16384
#define ALPHA_LR 0.2f
#define NEGV -9.0e15f
#define VTILE (HD_SZ * 32)   // elements per (g,b,jt) V-tile: 384 d x 32 j
#define PSLICE ((size_t)M_SZ * HD_SZ)  // elems per g-slice of partials

__device__ __forceinline__ float bf2f(ushort_t u) { return __uint_as_float(((uint_t)u) << 16); }
__device__ __forceinline__ ushort_t f2bf(float f) {
  uint_t x = __float_as_uint(f);
  return (ushort_t)((x + 0x7fffu + ((x >> 16) & 1u)) >> 16);
}

// Async global->LDS, 16B per lane. LDS dest is wave-uniform base + lane*16.
__device__ __forceinline__ void gload_lds16(const ushort_t* g, ushort_t* l) {
  __builtin_amdgcn_global_load_lds(
      (const __attribute__((address_space(1))) uint_t*)(const void*)g,
      (__attribute__((address_space(3))) uint_t*)(void*)l, 16, 0, 0);
}

// ---------------------------------------------------------------------------
// LDS-tiled transpose + downcast: dst[c*R+r] = bf16(src[r*C+c]), batched z.
// 64x64 tile; both global reads and writes coalesced (the old per-element
// version scattered 2B stores at stride R -> ~64B write-allocate per elem).
// ---------------------------------------------------------------------------
__global__ __launch_bounds__(256) void transpose_tile(
    const float* __restrict__ src, ushort_t* __restrict__ dst, int R, int C) {
  __shared__ float t[64][65];
  size_t base = (size_t)blockIdx.z * R * C;
  int c0 = blockIdx.x * 64, r0 = blockIdx.y * 64;
  int tx = threadIdx.x & 63, ty = threadIdx.x >> 6;
#pragma unroll
  for (int i = 0; i < 16; i++) {
    int r = ty * 16 + i;
    t[r][tx] = src[base + (size_t)(r0 + r) * C + c0 + tx];
  }
  __syncthreads();
#pragma unroll
  for (int i = 0; i < 16; i++) {
    int c = ty * 16 + i;
    dst[base + (size_t)(c0 + c) * R + r0 + tx] = f2bf(t[tx][c]);
  }
}

// ---------------------------------------------------------------------------
// Pack adjacency ints (0/1) into bitmask words: am[i>>5] bit (i&31) = adj[i]!=0
// ---------------------------------------------------------------------------
__global__ __launch_bounds__(256) void pack_adj(
    const int* __restrict__ adj, uint_t* __restrict__ am) {
  size_t i = (size_t)blockIdx.x * 256 + threadIdx.x;
  unsigned long long mask = __ballot(adj[i] != 0);
  int lane = threadIdx.x & 63;
  if ((lane & 31) == 0) am[i >> 5] = (uint_t)(mask >> (lane & 32));
}

// ---------------------------------------------------------------------------
// Zero-init (for e1/e2 atomic accumulation).
// ---------------------------------------------------------------------------
__global__ __launch_bounds__(256) void zero_kernel(float* __restrict__ p) {
  p[(size_t)blockIdx.x * 256 + threadIdx.x] = 0.f;
}

// ---------------------------------------------------------------------------
// Content gates + x downcast fused: gate reads every x element exactly once
// (block n covers all (b,f)), so emit xb = bf16(x) here for free and delete
// the separate cast pass (-75 MB of traffic).
// ---------------------------------------------------------------------------
__global__ __launch_bounds__(256) void gate_kernel(
    const float* __restrict__ x, const float* __restrict__ gate_w,
    const float* __restrict__ gate_b, float* __restrict__ cg,
    ushort_t* __restrict__ xb) {
  int n = blockIdx.x;
  int tid = threadIdx.x;
  float a0 = 0.f, a1 = 0.f, a2 = 0.f;
  for (int f = tid; f < FD_SZ; f += 256) {
    float s = 0.f;
#pragma unroll
    for (int b = 0; b < B_SZ; b++) {
      size_t off = ((size_t)b * N_SZ + n) * FD_SZ + f;
      float xv = x[off];
      xb[off] = f2bf(xv);
      s += xv;
    }
    float avg = s * (1.0f / B_SZ);
    a0 += avg * gate_w[f * 3 + 0];
    a1 += avg * gate_w[f * 3 + 1];
    a2 += avg * gate_w[f * 3 + 2];
  }
  for (int m = 1; m < 64; m <<= 1) {
    a0 += __shfl_xor(a0, m, 64);
    a1 += __shfl_xor(a1, m, 64);
    a2 += __shfl_xor(a2, m, 64);
  }
  __shared__ float red[3][4];
  int wave = tid >> 6, lane = tid & 63;
  if (lane == 0) { red[0][wave] = a0; red[1][wave] = a1; red[2][wave] = a2; }
  __syncthreads();
  if (tid == 0) {
    float l0 = red[0][0] + red[0][1] + red[0][2] + red[0][3] + gate_b[0];
    float l1 = red[1][0] + red[1][1] + red[1][2] + red[1][3] + gate_b[1];
    float l2 = red[2][0] + red[2][1] + red[2][2] + red[2][3] + gate_b[2];
    float mx = fmaxf(l0, fmaxf(l1, l2));
    float e0 = __expf(l0 - mx), e1 = __expf(l1 - mx), e2 = __expf(l2 - mx);
    float inv = 1.0f / (e0 + e1 + e2);
    cg[n * 3 + 0] = e0 * inv;
    cg[n * 3 + 1] = e1 * inv;
    cg[n * 3 + 2] = e2 * inv;
  }
}

// ---------------------------------------------------------------------------
// MFMA bf16 GEMM: C[M,Nc] = A[M,K] @ B[K,Nc] (+bias, +relu). All inputs bf16.
// Bt row-major [Nc,K]. 128x128 tile, BK=32, 4 waves 64x64 each.
// Staging via global_load_lds width=16.
// VFOUT: write C as V-tiles vf[(z*32+b)*16+jt][d][j2] bf16.
// EOUT (with VFOUT): also emit e1/e2 = V @ a1/a2 from the f32 accumulators
//   (l15 shfl-reduce + atomicAdd) -> deletes the e12 pass over 37.7 MB of vf.
// ARED3: A is the 3-slice bf16 partial buffer pf; stage sum_g pf[g] via
//   registers -> deletes the reduce3 pass.
// ---------------------------------------------------------------------------
template <bool RELU, bool OUTBF16, bool HASBIAS, bool VFOUT, bool EOUT, bool ARED3>
__global__ __launch_bounds__(256) void gemm_kernel(
    const ushort_t* __restrict__ Ab, size_t strideA,
    const ushort_t* __restrict__ Bt, size_t strideB,
    const float* __restrict__ bias,
    void* __restrict__ Cv, size_t strideC,
    int M, int K, int Nc,
    const float* __restrict__ av, float* __restrict__ e1,
    float* __restrict__ e2) {
  __shared__ __attribute__((aligned(16))) ushort_t As[128 * 32];
  __shared__ __attribute__((aligned(16))) ushort_t Bs[128 * 32];
  int tid = threadIdx.x, wave = tid >> 6, lane = tid & 63;
  int m0 = blockIdx.y * 128, n0 = blockIdx.x * 128;
  const ushort_t* A = Ab + (size_t)blockIdx.z * strideA;
  const ushort_t* Bb = Bt + (size_t)blockIdx.z * strideB;

  f32x4 acc[4][4];
  f32x4 z4 = {0.f, 0.f, 0.f, 0.f};
#pragma unroll
  for (int i = 0; i < 4; i++)
#pragma unroll
    for (int j = 0; j < 4; j++) acc[i][j] = z4;

  int wm = (wave & 1) * 64, wn = (wave >> 1) * 64;
  int srow = lane >> 2, schk = (lane & 3) * 8;

  for (int kt = 0; kt < K; kt += 32) {
    u32x4 aw[2];
    if (ARED3) {
#pragma unroll
      for (int i = 0; i < 2; i++) {
        const ushort_t* ap =
            A + (size_t)(m0 + wave * 32 + i * 16 + srow) * K + kt + schk;
        u16x8 q0 = *(const u16x8*)ap;
        u16x8 q1 = *(const u16x8*)(ap + PSLICE);
        u16x8 q2 = *(const u16x8*)(ap + 2 * PSLICE);
        union { ushort_t us[8]; u32x4 v; } pk;
#pragma unroll
        for (int k = 0; k < 8; k++)
          pk.us[k] = f2bf(bf2f(q0[k]) + bf2f(q1[k]) + bf2f(q2[k]));
        aw[i] = pk.v;
      }
    }
    __syncthreads();  // previous tile's frag reads done (kt=0: harmless)
#pragma unroll
    for (int i = 0; i < 2; i++) {
      int rowBase = wave * 32 + i * 16;
      if (ARED3) {
        *(u32x4*)(As + rowBase * 32 + lane * 8) = aw[i];
      } else {
        gload_lds16(A + (size_t)(m0 + rowBase + srow) * K + kt + schk,
                    As + rowBase * 32);
      }
      gload_lds16(Bb + (size_t)(n0 + rowBase + srow) * K + kt + schk,
                  Bs + rowBase * 32);
    }
    __syncthreads();  // vmcnt/lgkm drained before barrier -> tiles visible
    bf16x8 af[4], bfr[4];
#pragma unroll
    for (int t = 0; t < 4; t++) {
      af[t] = *(const bf16x8*)(As + (wm + t * 16 + (lane & 15)) * 32 + (lane >> 4) * 8);
      bfr[t] = *(const bf16x8*)(Bs + (wn + t * 16 + (lane & 15)) * 32 + (lane >> 4) * 8);
    }
#pragma unroll
    for (int mt = 0; mt < 4; mt++)
#pragma unroll
      for (int nt = 0; nt < 4; nt++)
        acc[mt][nt] = __builtin_amdgcn_mfma_f32_16x16x32_bf16(af[mt], bfr[nt], acc[mt][nt], 0, 0, 0);
  }

  if (VFOUT) {
#pragma unroll
    for (int mt = 0; mt < 4; mt++) {
#pragma unroll
      for (int nt = 0; nt < 4; nt++) {
        int d = n0 + wn + nt * 16 + (lane & 15);
        int gm = m0 + wm + mt * 16 + (lane >> 4) * 4;
        int b = gm >> 9, jt = (gm >> 5) & 15, j2 = gm & 31;
        u16x4 pk;
#pragma unroll
        for (int r2 = 0; r2 < 4; r2++) pk[r2] = f2bf(acc[mt][nt][r2]);
        size_t off = ((size_t)((blockIdx.z * B_SZ + b) * 16 + jt)) * VTILE + (size_t)d * 32 + j2;
        *(u16x4*)((ushort_t*)Cv + off) = pk;
      }
    }
    if (EOUT) {
      int g = blockIdx.z;
      float a1v[4], a2v[4];
#pragma unroll
      for (int nt = 0; nt < 4; nt++) {
        int d = n0 + wn + nt * 16 + (lane & 15);
        a1v[nt] = av[g * 2 * HD_SZ + d];
        a2v[nt] = av[g * 2 * HD_SZ + HD_SZ + d];
      }
#pragma unroll
      for (int mt = 0; mt < 4; mt++)
#pragma unroll
        for (int r2 = 0; r2 < 4; r2++) {
          float p1 = 0.f, p2 = 0.f;
#pragma unroll
          for (int nt = 0; nt < 4; nt++) {
            p1 += acc[mt][nt][r2] * a1v[nt];
            p2 += acc[mt][nt][r2] * a2v[nt];
          }
#pragma unroll
          for (int msk = 1; msk < 16; msk <<= 1) {
            p1 += __shfl_xor(p1, msk, 64);
            p2 += __shfl_xor(p2, msk, 64);
          }
          if ((lane & 15) == 0) {
            int gm = m0 + wm + mt * 16 + (lane >> 4) * 4 + r2;
            atomicAdd(&e1[(size_t)g * M_SZ + gm], p1);
            atomicAdd(&e2[(size_t)g * M_SZ + gm], p2);
          }
        }
    }
  } else {
#pragma unroll
    for (int mt = 0; mt < 4; mt++) {
#pragma unroll
      for (int nt = 0; nt < 4; nt++) {
        int gn = n0 + wn + nt * 16 + (lane & 15);
        float bvs = HASBIAS ? bias[gn] : 0.f;
#pragma unroll
        for (int r2 = 0; r2 < 4; r2++) {
          int gm = m0 + wm + mt * 16 + (lane >> 4) * 4 + r2;
          float v = acc[mt][nt][r2] + bvs;
          if (RELU) v = v > 0.f ? v : 0.f;
          size_t off = (size_t)blockIdx.z * strideC + (size_t)gm * Nc + gn;
          if (OUTBF16) ((ushort_t*)Cv)[off] = f2bf(v);
          else ((float*)Cv)[off] = v;
        }
      }
    }
  }
}

// ---------------------------------------------------------------------------
// Attention (MFMA PV) + ELU + LN1 + g-weight.  QBLK=32, SPLIT-G.
// Grid (16, 32, 3): block = (i0-tile, b, g). Partials pf[g][m][d] in d_out.
// XCD swizzle: same b -> same L%8 -> same XCD L2 for the (g,b) V-tile.
// ---------------------------------------------------------------------------
__global__ __launch_bounds__(512, 4) void attn_kernel(
    const uint_t* __restrict__ adjm, const ushort_t* __restrict__ vf,
    const float* __restrict__ e1, const float* __restrict__ e2,
    const float* __restrict__ cg, const float* __restrict__ log_unc,
    const float* __restrict__ ln1g, const float* __restrict__ ln1b,
    ushort_t* __restrict__ pf) {
  __shared__ __attribute__((aligned(16))) ushort_t Pb[32][520];  // +8 pad
  __shared__ float e2s[512];
  __shared__ float e1r[32];
  __shared__ uint_t amS[32][16];
  __shared__ float lng[HD_SZ], lnb[HD_SZ];
  __shared__ float cgr[32];     // cg for own g only
  __shared__ float s1s[32][8], s2s[32][8];

  int tid = threadIdx.x, wave = tid >> 6, lane = tid & 63;
  int quad = lane >> 4, l15 = lane & 15;
  int g = blockIdx.z;
  int L = blockIdx.x + (blockIdx.y << 4);
  int b = (L & 7) + ((L >> 7) << 3);
  int i0 = ((L >> 3) & 15) * 32;

  float iv0 = 1.f / (__expf(log_unc[0]) + 1e-8f);
  float iv1 = 1.f / (__expf(log_unc[1]) + 1e-8f);
  float iv2 = 1.f / (__expf(log_unc[2]) + 1e-8f);
  float mxa = fmaxf(iv0, fmaxf(iv1, iv2));
  float w0 = __expf(iv0 - mxa), w1 = __expf(iv1 - mxa), w2 = __expf(iv2 - mxa);
  float wsum = 1.f / (w0 + w1 + w2);
  float attwg = (g == 0 ? w0 : (g == 1 ? w1 : w2)) * wsum;

  if (tid < HD_SZ) {
    lng[tid] = ln1g[tid];
    lnb[tid] = ln1b[tid];
  }
  if (tid < 32) {
    cgr[tid] = cg[(i0 + tid) * 3 + g];
    e1r[tid] = e1[((size_t)g * B_SZ + b) * N_SZ + i0 + tid];
  }
  amS[tid >> 4][tid & 15] = adjm[((size_t)g * N_SZ + i0 + (tid >> 4)) * 16 + (tid & 15)];
  e2s[tid] = e2[((size_t)g * B_SZ + b) * N_SZ + tid];
  __syncthreads();

  // scores + softmax, in-register; wave owns rows {4w .. 4w+3}
#pragma unroll
  for (int rr = 0; rr < 4; rr++) {
    int rw = wave * 4 + rr;
    float e1v = e1r[rw];
    float sv[8];
    float m = -3.0e38f;
#pragma unroll
    for (int jj = 0; jj < 8; jj++) {
      int j = lane + jj * 64;
      float s = e1v + e2s[j];
      s = s > 0.f ? s : ALPHA_LR * s;
      uint_t mw = amS[rw][(lane >> 5) + jj * 2];  // broadcast per half-wave
      s = ((mw >> (j & 31)) & 1u) ? s : NEGV;
      sv[jj] = s;
      m = fmaxf(m, s);
    }
    for (int msk = 1; msk < 64; msk <<= 1) m = fmaxf(m, __shfl_xor(m, msk, 64));
    float sum = 0.f;
#pragma unroll
    for (int jj = 0; jj < 8; jj++) {
      float e = __expf(sv[jj] - m);
      sv[jj] = e;
      sum += e;
    }
    for (int msk = 1; msk < 64; msk <<= 1) sum += __shfl_xor(sum, msk, 64);
    float inv = 1.0f / sum;
#pragma unroll
    for (int jj = 0; jj < 8; jj++) Pb[rw][lane + jj * 64] = f2bf(sv[jj] * inv);
  }
  __syncthreads();

  // PV via MFMA: O[32 x 48-per-wave] = P[32 x 512] @ V; 2 P-tiles share V
  f32x4 acc[2][3];
  f32x4 z4 = {0.f, 0.f, 0.f, 0.f};
#pragma unroll
  for (int mt = 0; mt < 2; mt++)
#pragma unroll
    for (int t = 0; t < 3; t++) acc[mt][t] = z4;
  const ushort_t* vbase = vf + ((size_t)(g * B_SZ + b) * 16) * VTILE;
#pragma unroll 2
  for (int j0 = 0; j0 < N_SZ; j0 += 32) {
    const ushort_t* vtile = vbase + (size_t)(j0 >> 5) * VTILE;
    bf16x8 af0 = *(const bf16x8*)(&Pb[l15][j0 + quad * 8]);
    bf16x8 af1 = *(const bf16x8*)(&Pb[16 + l15][j0 + quad * 8]);
#pragma unroll
    for (int t = 0; t < 3; t++) {
      bf16x8 bf = *(const bf16x8*)(vtile + (wave * 48 + t * 16 + l15) * 32 + quad * 8);
      acc[0][t] = __builtin_amdgcn_mfma_f32_16x16x32_bf16(af0, bf, acc[0][t], 0, 0, 0);
      acc[1][t] = __builtin_amdgcn_mfma_f32_16x16x32_bf16(af1, bf, acc[1][t], 0, 0, 0);
    }
  }

  // epilogue: ELU (in-place in acc), LN stats per row, weight, write partial
  float ps1[2][4], ps2[2][4];
#pragma unroll
  for (int mt = 0; mt < 2; mt++)
#pragma unroll
    for (int r = 0; r < 4; r++) { ps1[mt][r] = 0.f; ps2[mt][r] = 0.f; }
#pragma unroll
  for (int mt = 0; mt < 2; mt++)
#pragma unroll
    for (int t = 0; t < 3; t++)
#pragma unroll
      for (int r = 0; r < 4; r++) {
        float v = acc[mt][t][r];
        v = v > 0.f ? v : __expf(v) - 1.f;
        acc[mt][t][r] = v;
        ps1[mt][r] += v;
        ps2[mt][r] += v * v;
      }
#pragma unroll
  for (int msk = 1; msk < 16; msk <<= 1) {
#pragma unroll
    for (int mt = 0; mt < 2; mt++)
#pragma unroll
      for (int r = 0; r < 4; r++) {
        ps1[mt][r] += __shfl_xor(ps1[mt][r], msk, 64);
        ps2[mt][r] += __shfl_xor(ps2[mt][r], msk, 64);
      }
  }
  if (l15 == 0) {
#pragma unroll
    for (int mt = 0; mt < 2; mt++)
#pragma unroll
      for (int r = 0; r < 4; r++) {
        s1s[mt * 16 + quad * 4 + r][wave] = ps1[mt][r];
        s2s[mt * 16 + quad * 4 + r][wave] = ps2[mt][r];
      }
  }
  __syncthreads();
#pragma unroll
  for (int mt = 0; mt < 2; mt++)
#pragma unroll
    for (int r = 0; r < 4; r++) {
      int row = mt * 16 + quad * 4 + r;
      float S1 = 0.f, S2 = 0.f;
#pragma unroll
      for (int w = 0; w < 8; w++) {
        S1 += s1s[row][w];
        S2 += s2s[row][w];
      }
      float mean = S1 * (1.f / HD_SZ);
      float var = S2 * (1.f / HD_SZ) - mean * mean;
      float rs = rsqrtf(var + 1e-5f);
      float wgt = 0.7f * attwg + 0.3f * cgr[row];
      size_t rowo = (size_t)g * PSLICE + ((size_t)b * N_SZ + i0 + row) * HD_SZ;
#pragma unroll
      for (int t = 0; t < 3; t++) {
        int d = wave * 48 + t * 16 + l15;
        pf[rowo + d] = f2bf(wgt * ((acc[mt][t][r] - mean) * rs * lng[d] + lnb[d]));
      }
    }
}

// ---------------------------------------------------------------------------
// LN2 + residual sigmoid gate. One block per (b,n) row. proj bf16, x/out f32.
// ---------------------------------------------------------------------------
__global__ __launch_bounds__(256) void final_kernel(
    const ushort_t* __restrict__ projbf, const float* __restrict__ x,
    const float* __restrict__ ln2g, const float* __restrict__ ln2b,
    float* __restrict__ out) {
  int row = blockIdx.x;
  int tid = threadIdx.x, wave = tid >> 6, lane = tid & 63;
  const ushort_t* pr = projbf + (size_t)row * FD_SZ;
  const float* xr = x + (size_t)row * FD_SZ;
  float v[3], xv[3];
  float s1 = 0.f, s2 = 0.f;
#pragma unroll
  for (int k = 0; k < 3; k++) {
    int c = tid + k * 256;
    v[k] = bf2f(pr[c]);
    xv[k] = xr[c];
    s1 += v[k];
    s2 += v[k] * v[k];
  }
  for (int m = 1; m < 64; m <<= 1) {
    s1 += __shfl_xor(s1, m, 64);
    s2 += __shfl_xor(s2, m, 64);
  }
  __shared__ float rs1[4], rs2[4], rdt[4];
  if (lane == 0) { rs1[wave] = s1; rs2[wave] = s2; }
  __syncthreads();
  s1 = rs1[0] + rs1[1] + rs1[2] + rs1[3];
  s2 = rs2[0] + rs2[1] + rs2[2] + rs2[3];
  float mean = s1 * (1.f / FD_SZ);
  float var = s2 * (1.f / FD_SZ) - mean * mean;
  float rstd = rsqrtf(var + 1e-5f);
  float dot = 0.f;
  float pn[3];
#pragma unroll
  for (int k = 0; k < 3; k++) {
    int c = tid + k * 256;
    pn[k] = (v[k] - mean) * rstd * ln2g[c] + ln2b[c];
    dot += pn[k] * xv[k];
  }
  for (int m = 1; m < 64; m <<= 1) dot += __shfl_xor(dot, m, 64);
  if (lane == 0) rdt[wave] = dot;
  __syncthreads();
  dot = rdt[0] + rdt[1] + rdt[2] + rdt[3];
  float gv = 1.f / (1.f + __expf(-dot * (1.0f / 27.712812921102035f)));  // /sqrt(768)
#pragma unroll
  for (int k = 0; k < 3; k++) {
    int c = tid + k * 256;
    out[(size_t)row * FD_SZ + c] = gv * xv[k] + (1.f - gv) * pn[k];
  }
}

// ---------------------------------------------------------------------------
extern "C" void kernel_launch(void* const* d_in, const int* in_sizes, int n_in,
                              void* d_out, int out_size, void* d_ws, size_t ws_size,
                              hipStream_t stream) {
  (void)in_sizes; (void)n_in; (void)out_size; (void)ws_size;
  const float* x = (const float*)d_in[0];
  const int* adj = (const int*)d_in[1];
  const float* W = (const float*)d_in[2];
  const float* a = (const float*)d_in[3];
  const float* log_unc = (const float*)d_in[4];
  const float* gate_w = (const float*)d_in[5];
  const float* gate_b = (const float*)d_in[6];
  const float* ln1g = (const float*)d_in[7];
  const float* ln1b = (const float*)d_in[8];
  const float* w1 = (const float*)d_in[9];
  const float* b1 = (const float*)d_in[10];
  const float* w2 = (const float*)d_in[11];
  const float* b2 = (const float*)d_in[12];
  const float* ln2g = (const float*)d_in[13];
  const float* ln2b = (const float*)d_in[14];

  // Workspace (liveness-overlapped):
  //  [0          ) Wt      1,769,472   -> adjm (96 KB) after vf GEMM
  //  [1,769,472  ) w1t     294,912
  //  [2,064,384  ) w2t     589,824
  //  [2,654,208  ) cg      6,144
  //  [2,660,352  ) e1      196,608   (e2 contiguous after -> one zero pass)
  //  [2,856,960  ) e2      196,608
  //  [3,053,568  ) (free; was fusedbf)
  //  [15,636,480 ) vf      37,748,736 ; reused: t1bf / projbf
  // d_out (50.3 MB) triple-duty scratch: xb (bf16 x, 25.2 MB, live until vf
  // GEMM) -> pf (bf16 g-partials, 37.7 MB, attn -> t1 GEMM) -> final output.
  char* ws = (char*)d_ws;
  ushort_t* Wt      = (ushort_t*)(ws + 0);
  uint_t*   adjm    = (uint_t*)(ws + 0);            // over dead Wt (post-vf)
  ushort_t* w1t     = (ushort_t*)(ws + 1769472);
  ushort_t* w2t     = (ushort_t*)(ws + 2064384);
  float*    cg      = (float*)(ws + 2654208);
  float*    e1      = (float*)(ws + 2660352);
  float*    e2      = (float*)(ws + 2856960);
  ushort_t* vf      = (ushort_t*)(ws + 15636480);
  ushort_t* t1bf    = (ushort_t*)(ws + 15636480);   // over dead vf
  ushort_t* projbf  = (ushort_t*)(ws + 28219392);   // over dead vf
  ushort_t* xb      = (ushort_t*)d_out;             // scratch until vf GEMM
  ushort_t* pf      = (ushort_t*)d_out;             // scratch: attn partials

  transpose_tile<<<dim3(HD_SZ / 64, FD_SZ / 64, 3), 256, 0, stream>>>(W, Wt, FD_SZ, HD_SZ);
  transpose_tile<<<dim3(HD_SZ / 64, HD_SZ / 64, 1), 256, 0, stream>>>(w1, w1t, HD_SZ, HD_SZ);
  transpose_tile<<<dim3(FD_SZ / 64, HD_SZ / 64, 1), 256, 0, stream>>>(w2, w2t, HD_SZ, FD_SZ);

  // gates + x->bf16 downcast fused (gate touches every x element once)
  gate_kernel<<<dim3(N_SZ), 256, 0, stream>>>(x, gate_w, gate_b, cg, xb);

  // e1,e2 zero-init for atomic accumulation (contiguous 98304 floats)
  zero_kernel<<<dim3((2 * G_SZ * M_SZ) / 256), 256, 0, stream>>>(e1);

  // vf[g] = (x @ W[g]) in V-tile layout; epilogue also emits e1/e2
  gemm_kernel<false, true, false, true, true, false><<<dim3(3, 128, 3), 256, 0, stream>>>(
      xb, 0, Wt, (size_t)HD_SZ * FD_SZ, nullptr, vf, 0,
      M_SZ, FD_SZ, HD_SZ, a, e1, e2);

  // adj -> bitmask, into the now-dead Wt region (must follow the vf GEMM)
  pack_adj<<<dim3((G_SZ * N_SZ * N_SZ) / 256), 256, 0, stream>>>(adj, adjm);

  // split-g attention -> bf16 partials in d_out (xb dead after vf GEMM)
  attn_kernel<<<dim3(N_SZ / 32, B_SZ, G_SZ), 512, 0, stream>>>(
      adjm, vf, e1, e2, cg, log_unc, ln1g, ln1b, pf);

  // t1 = relu((sum_g pf[g]) @ w1 + b1); 3-slice sum folded into A-staging
  gemm_kernel<true, true, true, false, false, true><<<dim3(3, 128, 1), 256, 0, stream>>>(
      pf, 0, w1t, 0, b1, t1bf, 0, M_SZ, HD_SZ, HD_SZ, nullptr, nullptr, nullptr);
  // proj = t1 @ w2 + b2 (bf16 out)
  gemm_kernel<false, true, true, false, false, false><<<dim3(6, 128, 1), 256, 0, stream>>>(
      t1bf, 0, w2t, 0, b2, projbf, 0, M_SZ, HD_SZ, FD_SZ, nullptr, nullptr, nullptr);

  final_kernel<<<dim3(M_SZ), 256, 0, stream>>>(projbf, x, ln2g, ln2b, (float*)d_out);
}

// Round 8
// 323.335 us; speedup vs baseline: 1.1873x; 1.0133x over previous
//
#include <hip/hip_runtime.h>

typedef unsigned short ushort_t;
typedef unsigned int uint_t;
typedef __bf16 bf16x8 __attribute__((ext_vector_type(8)));
typedef float f32x4 __attribute__((ext_vector_type(4)));
typedef unsigned int u32x4 __attribute__((ext_vector_type(4)));
typedef unsigned short u16x4 __attribute__((ext_vector_type(4)));
typedef unsigned short u16x8 __attribute__((ext_vector_type(8)));

#define B_SZ 32
#define N_SZ 512
#define FD_SZ 768
#define HD_SZ 384
#define G_SZ 3
#define M_SZ (B_SZ * N_SZ)   // 16384
#define ALPHA_LR 0.2f
#define NEGV -9.0e15f
#define VTILE (HD_SZ * 32)   // elements per (g,b,jt) V-tile: 384 d x 32 j
#define PSLICE ((size_t)M_SZ * HD_SZ)  // elems per g-slice of partials
#define TILEE (128 * 32)     // elems per LDS GEMM tile buffer

__device__ __forceinline__ float bf2f(ushort_t u) { return __uint_as_float(((uint_t)u) << 16); }
__device__ __forceinline__ ushort_t f2bf(float f) {
  uint_t x = __float_as_uint(f);
  return (ushort_t)((x + 0x7fffu + ((x >> 16) & 1u)) >> 16);
}

// Async global->LDS, 16B per lane. LDS dest is wave-uniform base + lane*16.
__device__ __forceinline__ void gload_lds16(const ushort_t* g, ushort_t* l) {
  __builtin_amdgcn_global_load_lds(
      (const __attribute__((address_space(1))) uint_t*)(const void*)g,
      (__attribute__((address_space(3))) uint_t*)(void*)l, 16, 0, 0);
}

// ---------------------------------------------------------------------------
// LDS-tiled transpose + downcast: dst[c*R+r] = bf16(src[r*C+c]), batched z.
// ---------------------------------------------------------------------------
__global__ __launch_bounds__(256) void transpose_tile(
    const float* __restrict__ src, ushort_t* __restrict__ dst, int R, int C) {
  __shared__ float t[64][65];
  size_t base = (size_t)blockIdx.z * R * C;
  int c0 = blockIdx.x * 64, r0 = blockIdx.y * 64;
  int tx = threadIdx.x & 63, ty = threadIdx.x >> 6;
#pragma unroll
  for (int i = 0; i < 16; i++) {
    int r = ty * 16 + i;
    t[r][tx] = src[base + (size_t)(r0 + r) * C + c0 + tx];
  }
  __syncthreads();
#pragma unroll
  for (int i = 0; i < 16; i++) {
    int c = ty * 16 + i;
    dst[base + (size_t)(c0 + c) * R + r0 + tx] = f2bf(t[tx][c]);
  }
}

// ---------------------------------------------------------------------------
// Pack adjacency ints (0/1) into bitmask words: am[i>>5] bit (i&31) = adj[i]!=0
// ---------------------------------------------------------------------------
__global__ __launch_bounds__(256) void pack_adj(
    const int* __restrict__ adj, uint_t* __restrict__ am) {
  size_t i = (size_t)blockIdx.x * 256 + threadIdx.x;
  unsigned long long mask = __ballot(adj[i] != 0);
  int lane = threadIdx.x & 63;
  if ((lane & 31) == 0) am[i >> 5] = (uint_t)(mask >> (lane & 32));
}

// ---------------------------------------------------------------------------
// Zero-init (for e1/e2 atomic accumulation).
// ---------------------------------------------------------------------------
__global__ __launch_bounds__(256) void zero_kernel(float* __restrict__ p) {
  p[(size_t)blockIdx.x * 256 + threadIdx.x] = 0.f;
}

// ---------------------------------------------------------------------------
// Content gates + x downcast fused.
// ---------------------------------------------------------------------------
__global__ __launch_bounds__(256) void gate_kernel(
    const float* __restrict__ x, const float* __restrict__ gate_w,
    const float* __restrict__ gate_b, float* __restrict__ cg,
    ushort_t* __restrict__ xb) {
  int n = blockIdx.x;
  int tid = threadIdx.x;
  float a0 = 0.f, a1 = 0.f, a2 = 0.f;
  for (int f = tid; f < FD_SZ; f += 256) {
    float s = 0.f;
#pragma unroll
    for (int b = 0; b < B_SZ; b++) {
      size_t off = ((size_t)b * N_SZ + n) * FD_SZ + f;
      float xv = x[off];
      xb[off] = f2bf(xv);
      s += xv;
    }
    float avg = s * (1.0f / B_SZ);
    a0 += avg * gate_w[f * 3 + 0];
    a1 += avg * gate_w[f * 3 + 1];
    a2 += avg * gate_w[f * 3 + 2];
  }
  for (int m = 1; m < 64; m <<= 1) {
    a0 += __shfl_xor(a0, m, 64);
    a1 += __shfl_xor(a1, m, 64);
    a2 += __shfl_xor(a2, m, 64);
  }
  __shared__ float red[3][4];
  int wave = tid >> 6, lane = tid & 63;
  if (lane == 0) { red[0][wave] = a0; red[1][wave] = a1; red[2][wave] = a2; }
  __syncthreads();
  if (tid == 0) {
    float l0 = red[0][0] + red[0][1] + red[0][2] + red[0][3] + gate_b[0];
    float l1 = red[1][0] + red[1][1] + red[1][2] + red[1][3] + gate_b[1];
    float l2 = red[2][0] + red[2][1] + red[2][2] + red[2][3] + gate_b[2];
    float mx = fmaxf(l0, fmaxf(l1, l2));
    float e0 = __expf(l0 - mx), e1 = __expf(l1 - mx), e2 = __expf(l2 - mx);
    float inv = 1.0f / (e0 + e1 + e2);
    cg[n * 3 + 0] = e0 * inv;
    cg[n * 3 + 1] = e1 * inv;
    cg[n * 3 + 2] = e2 * inv;
  }
}

// ---------------------------------------------------------------------------
// MFMA bf16 GEMM: C[M,Nc] = A[M,K] @ B[K,Nc] (+bias, +relu). All inputs bf16.
// Bt row-major [Nc,K]. 128x128 tile, BK=32, 4 waves 64x64 each.
// DOUBLE-BUFFERED, 1 barrier/K-step (T3-minimum): prologue stages tile 0;
// each iter: barrier (drains last stage) -> issue stage(next, other buf) ->
// ds_read+MFMA current buf. The vmcnt(0) drain at the NEXT barrier happens
// after a full compute phase, hiding the global-load latency that the old
// stage->barrier->compute order exposed on every K-step (~1500 cy/step at
// 2 blocks/CU, round-6 counters). Plain __syncthreads only — race-safe:
// readers of buf^1 only touch it after the next barrier, and each wave's
// own gload_lds is vmcnt(0)-drained before that barrier.
// VFOUT: write C as V-tiles. EOUT: fused e1/e2 = V @ a1/a2 (atomicAdd).
// ARED3: A = sum of 3 bf16 partial slices, staged via regs + ds_write.
// ---------------------------------------------------------------------------
template <bool RELU, bool OUTBF16, bool HASBIAS, bool VFOUT, bool EOUT, bool ARED3>
__global__ __launch_bounds__(256) void gemm_kernel(
    const ushort_t* __restrict__ Ab, size_t strideA,
    const ushort_t* __restrict__ Bt, size_t strideB,
    const float* __restrict__ bias,
    void* __restrict__ Cv, size_t strideC,
    int M, int K, int Nc,
    const float* __restrict__ av, float* __restrict__ e1,
    float* __restrict__ e2) {
  __shared__ __attribute__((aligned(16))) ushort_t As[2 * TILEE];
  __shared__ __attribute__((aligned(16))) ushort_t Bs[2 * TILEE];
  int tid = threadIdx.x, wave = tid >> 6, lane = tid & 63;
  int m0 = blockIdx.y * 128, n0 = blockIdx.x * 128;
  const ushort_t* A = Ab + (size_t)blockIdx.z * strideA;
  const ushort_t* Bb = Bt + (size_t)blockIdx.z * strideB;

  f32x4 acc[4][4];
  f32x4 z4 = {0.f, 0.f, 0.f, 0.f};
#pragma unroll
  for (int i = 0; i < 4; i++)
#pragma unroll
    for (int j = 0; j < 4; j++) acc[i][j] = z4;

  int wm = (wave & 1) * 64, wn = (wave >> 1) * 64;
  int srow = lane >> 2, schk = (lane & 3) * 8;

  // stage K-tile kt into buffer buf (issue only; drained at next barrier)
  auto stage = [&](int buf, int kt) {
    ushort_t* Ad = As + buf * TILEE;
    ushort_t* Bd = Bs + buf * TILEE;
#pragma unroll
    for (int i = 0; i < 2; i++) {
      int rowBase = wave * 32 + i * 16;
      if (ARED3) {
        const ushort_t* ap =
            A + (size_t)(m0 + rowBase + srow) * K + kt + schk;
        u16x8 q0 = *(const u16x8*)ap;
        u16x8 q1 = *(const u16x8*)(ap + PSLICE);
        u16x8 q2 = *(const u16x8*)(ap + 2 * PSLICE);
        union { ushort_t us[8]; u32x4 v; } pk;
#pragma unroll
        for (int k = 0; k < 8; k++)
          pk.us[k] = f2bf(bf2f(q0[k]) + bf2f(q1[k]) + bf2f(q2[k]));
        *(u32x4*)(Ad + rowBase * 32 + lane * 8) = pk.v;
      } else {
        gload_lds16(A + (size_t)(m0 + rowBase + srow) * K + kt + schk,
                    Ad + rowBase * 32);
      }
      gload_lds16(Bb + (size_t)(n0 + rowBase + srow) * K + kt + schk,
                  Bd + rowBase * 32);
    }
  };

  stage(0, 0);
  int cur = 0;
  for (int kt = 0; kt < K; kt += 32) {
    __syncthreads();  // drains stage(cur,kt); next-buf readers already past
    if (kt + 32 < K) stage(cur ^ 1, kt + 32);
    const ushort_t* Ar = As + cur * TILEE;
    const ushort_t* Br = Bs + cur * TILEE;
    bf16x8 af[4], bfr[4];
#pragma unroll
    for (int t = 0; t < 4; t++) {
      af[t] = *(const bf16x8*)(Ar + (wm + t * 16 + (lane & 15)) * 32 + (lane >> 4) * 8);
      bfr[t] = *(const bf16x8*)(Br + (wn + t * 16 + (lane & 15)) * 32 + (lane >> 4) * 8);
    }
#pragma unroll
    for (int mt = 0; mt < 4; mt++)
#pragma unroll
      for (int nt = 0; nt < 4; nt++)
        acc[mt][nt] = __builtin_amdgcn_mfma_f32_16x16x32_bf16(af[mt], bfr[nt], acc[mt][nt], 0, 0, 0);
    cur ^= 1;
  }

  if (VFOUT) {
#pragma unroll
    for (int mt = 0; mt < 4; mt++) {
#pragma unroll
      for (int nt = 0; nt < 4; nt++) {
        int d = n0 + wn + nt * 16 + (lane & 15);
        int gm = m0 + wm + mt * 16 + (lane >> 4) * 4;
        int b = gm >> 9, jt = (gm >> 5) & 15, j2 = gm & 31;
        u16x4 pk;
#pragma unroll
        for (int r2 = 0; r2 < 4; r2++) pk[r2] = f2bf(acc[mt][nt][r2]);
        size_t off = ((size_t)((blockIdx.z * B_SZ + b) * 16 + jt)) * VTILE + (size_t)d * 32 + j2;
        *(u16x4*)((ushort_t*)Cv + off) = pk;
      }
    }
    if (EOUT) {
      int g = blockIdx.z;
      float a1v[4], a2v[4];
#pragma unroll
      for (int nt = 0; nt < 4; nt++) {
        int d = n0 + wn + nt * 16 + (lane & 15);
        a1v[nt] = av[g * 2 * HD_SZ + d];
        a2v[nt] = av[g * 2 * HD_SZ + HD_SZ + d];
      }
#pragma unroll
      for (int mt = 0; mt < 4; mt++)
#pragma unroll
        for (int r2 = 0; r2 < 4; r2++) {
          float p1 = 0.f, p2 = 0.f;
#pragma unroll
          for (int nt = 0; nt < 4; nt++) {
            p1 += acc[mt][nt][r2] * a1v[nt];
            p2 += acc[mt][nt][r2] * a2v[nt];
          }
#pragma unroll
          for (int msk = 1; msk < 16; msk <<= 1) {
            p1 += __shfl_xor(p1, msk, 64);
            p2 += __shfl_xor(p2, msk, 64);
          }
          if ((lane & 15) == 0) {
            int gm = m0 + wm + mt * 16 + (lane >> 4) * 4 + r2;
            atomicAdd(&e1[(size_t)g * M_SZ + gm], p1);
            atomicAdd(&e2[(size_t)g * M_SZ + gm], p2);
          }
        }
    }
  } else {
#pragma unroll
    for (int mt = 0; mt < 4; mt++) {
#pragma unroll
      for (int nt = 0; nt < 4; nt++) {
        int gn = n0 + wn + nt * 16 + (lane & 15);
        float bvs = HASBIAS ? bias[gn] : 0.f;
#pragma unroll
        for (int r2 = 0; r2 < 4; r2++) {
          int gm = m0 + wm + mt * 16 + (lane >> 4) * 4 + r2;
          float v = acc[mt][nt][r2] + bvs;
          if (RELU) v = v > 0.f ? v : 0.f;
          size_t off = (size_t)blockIdx.z * strideC + (size_t)gm * Nc + gn;
          if (OUTBF16) ((ushort_t*)Cv)[off] = f2bf(v);
          else ((float*)Cv)[off] = v;
        }
      }
    }
  }
}

// ---------------------------------------------------------------------------
// Attention (MFMA PV) + ELU + LN1 + g-weight.  QBLK=32, SPLIT-G.
// Grid (16, 32, 3): block = (i0-tile, b, g). Partials pf[g][m][d] in d_out.
// XCD swizzle: same b -> same L%8 -> same XCD L2 for the (g,b) V-tile.
// ---------------------------------------------------------------------------
__global__ __launch_bounds__(512, 4) void attn_kernel(
    const uint_t* __restrict__ adjm, const ushort_t* __restrict__ vf,
    const float* __restrict__ e1, const float* __restrict__ e2,
    const float* __restrict__ cg, const float* __restrict__ log_unc,
    const float* __restrict__ ln1g, const float* __restrict__ ln1b,
    ushort_t* __restrict__ pf) {
  __shared__ __attribute__((aligned(16))) ushort_t Pb[32][520];  // +8 pad
  __shared__ float e2s[512];
  __shared__ float e1r[32];
  __shared__ uint_t amS[32][16];
  __shared__ float lng[HD_SZ], lnb[HD_SZ];
  __shared__ float cgr[32];     // cg for own g only
  __shared__ float s1s[32][8], s2s[32][8];

  int tid = threadIdx.x, wave = tid >> 6, lane = tid & 63;
  int quad = lane >> 4, l15 = lane & 15;
  int g = blockIdx.z;
  int L = blockIdx.x + (blockIdx.y << 4);
  int b = (L & 7) + ((L >> 7) << 3);
  int i0 = ((L >> 3) & 15) * 32;

  float iv0 = 1.f / (__expf(log_unc[0]) + 1e-8f);
  float iv1 = 1.f / (__expf(log_unc[1]) + 1e-8f);
  float iv2 = 1.f / (__expf(log_unc[2]) + 1e-8f);
  float mxa = fmaxf(iv0, fmaxf(iv1, iv2));
  float w0 = __expf(iv0 - mxa), w1 = __expf(iv1 - mxa), w2 = __expf(iv2 - mxa);
  float wsum = 1.f / (w0 + w1 + w2);
  float attwg = (g == 0 ? w0 : (g == 1 ? w1 : w2)) * wsum;

  if (tid < HD_SZ) {
    lng[tid] = ln1g[tid];
    lnb[tid] = ln1b[tid];
  }
  if (tid < 32) {
    cgr[tid] = cg[(i0 + tid) * 3 + g];
    e1r[tid] = e1[((size_t)g * B_SZ + b) * N_SZ + i0 + tid];
  }
  amS[tid >> 4][tid & 15] = adjm[((size_t)g * N_SZ + i0 + (tid >> 4)) * 16 + (tid & 15)];
  e2s[tid] = e2[((size_t)g * B_SZ + b) * N_SZ + tid];
  __syncthreads();

  // scores + softmax, in-register; wave owns rows {4w .. 4w+3}
#pragma unroll
  for (int rr = 0; rr < 4; rr++) {
    int rw = wave * 4 + rr;
    float e1v = e1r[rw];
    float sv[8];
    float m = -3.0e38f;
#pragma unroll
    for (int jj = 0; jj < 8; jj++) {
      int j = lane + jj * 64;
      float s = e1v + e2s[j];
      s = s > 0.f ? s : ALPHA_LR * s;
      uint_t mw = amS[rw][(lane >> 5) + jj * 2];  // broadcast per half-wave
      s = ((mw >> (j & 31)) & 1u) ? s : NEGV;
      sv[jj] = s;
      m = fmaxf(m, s);
    }
    for (int msk = 1; msk < 64; msk <<= 1) m = fmaxf(m, __shfl_xor(m, msk, 64));
    float sum = 0.f;
#pragma unroll
    for (int jj = 0; jj < 8; jj++) {
      float e = __expf(sv[jj] - m);
      sv[jj] = e;
      sum += e;
    }
    for (int msk = 1; msk < 64; msk <<= 1) sum += __shfl_xor(sum, msk, 64);
    float inv = 1.0f / sum;
#pragma unroll
    for (int jj = 0; jj < 8; jj++) Pb[rw][lane + jj * 64] = f2bf(sv[jj] * inv);
  }
  __syncthreads();

  // PV via MFMA: O[32 x 48-per-wave] = P[32 x 512] @ V; 2 P-tiles share V
  f32x4 acc[2][3];
  f32x4 z4 = {0.f, 0.f, 0.f, 0.f};
#pragma unroll
  for (int mt = 0; mt < 2; mt++)
#pragma unroll
    for (int t = 0; t < 3; t++) acc[mt][t] = z4;
  const ushort_t* vbase = vf + ((size_t)(g * B_SZ + b) * 16) * VTILE;
#pragma unroll 2
  for (int j0 = 0; j0 < N_SZ; j0 += 32) {
    const ushort_t* vtile = vbase + (size_t)(j0 >> 5) * VTILE;
    bf16x8 af0 = *(const bf16x8*)(&Pb[l15][j0 + quad * 8]);
    bf16x8 af1 = *(const bf16x8*)(&Pb[16 + l15][j0 + quad * 8]);
#pragma unroll
    for (int t = 0; t < 3; t++) {
      bf16x8 bf = *(const bf16x8*)(vtile + (wave * 48 + t * 16 + l15) * 32 + quad * 8);
      acc[0][t] = __builtin_amdgcn_mfma_f32_16x16x32_bf16(af0, bf, acc[0][t], 0, 0, 0);
      acc[1][t] = __builtin_amdgcn_mfma_f32_16x16x32_bf16(af1, bf, acc[1][t], 0, 0, 0);
    }
  }

  // epilogue: ELU (in-place in acc), LN stats per row, weight, write partial
  float ps1[2][4], ps2[2][4];
#pragma unroll
  for (int mt = 0; mt < 2; mt++)
#pragma unroll
    for (int r = 0; r < 4; r++) { ps1[mt][r] = 0.f; ps2[mt][r] = 0.f; }
#pragma unroll
  for (int mt = 0; mt < 2; mt++)
#pragma unroll
    for (int t = 0; t < 3; t++)
#pragma unroll
      for (int r = 0; r < 4; r++) {
        float v = acc[mt][t][r];
        v = v > 0.f ? v : __expf(v) - 1.f;
        acc[mt][t][r] = v;
        ps1[mt][r] += v;
        ps2[mt][r] += v * v;
      }
#pragma unroll
  for (int msk = 1; msk < 16; msk <<= 1) {
#pragma unroll
    for (int mt = 0; mt < 2; mt++)
#pragma unroll
      for (int r = 0; r < 4; r++) {
        ps1[mt][r] += __shfl_xor(ps1[mt][r], msk, 64);
        ps2[mt][r] += __shfl_xor(ps2[mt][r], msk, 64);
      }
  }
  if (l15 == 0) {
#pragma unroll
    for (int mt = 0; mt < 2; mt++)
#pragma unroll
      for (int r = 0; r < 4; r++) {
        s1s[mt * 16 + quad * 4 + r][wave] = ps1[mt][r];
        s2s[mt * 16 + quad * 4 + r][wave] = ps2[mt][r];
      }
  }
  __syncthreads();
#pragma unroll
  for (int mt = 0; mt < 2; mt++)
#pragma unroll
    for (int r = 0; r < 4; r++) {
      int row = mt * 16 + quad * 4 + r;
      float S1 = 0.f, S2 = 0.f;
#pragma unroll
      for (int w = 0; w < 8; w++) {
        S1 += s1s[row][w];
        S2 += s2s[row][w];
      }
      float mean = S1 * (1.f / HD_SZ);
      float var = S2 * (1.f / HD_SZ) - mean * mean;
      float rs = rsqrtf(var + 1e-5f);
      float wgt = 0.7f * attwg + 0.3f * cgr[row];
      size_t rowo = (size_t)g * PSLICE + ((size_t)b * N_SZ + i0 + row) * HD_SZ;
#pragma unroll
      for (int t = 0; t < 3; t++) {
        int d = wave * 48 + t * 16 + l15;
        pf[rowo + d] = f2bf(wgt * ((acc[mt][t][r] - mean) * rs * lng[d] + lnb[d]));
      }
    }
}

// ---------------------------------------------------------------------------
// LN2 + residual sigmoid gate. One block per (b,n) row. proj bf16, x/out f32.
// ---------------------------------------------------------------------------
__global__ __launch_bounds__(256) void final_kernel(
    const ushort_t* __restrict__ projbf, const float* __restrict__ x,
    const float* __restrict__ ln2g, const float* __restrict__ ln2b,
    float* __restrict__ out) {
  int row = blockIdx.x;
  int tid = threadIdx.x, wave = tid >> 6, lane = tid & 63;
  const ushort_t* pr = projbf + (size_t)row * FD_SZ;
  const float* xr = x + (size_t)row * FD_SZ;
  float v[3], xv[3];
  float s1 = 0.f, s2 = 0.f;
#pragma unroll
  for (int k = 0; k < 3; k++) {
    int c = tid + k * 256;
    v[k] = bf2f(pr[c]);
    xv[k] = xr[c];
    s1 += v[k];
    s2 += v[k] * v[k];
  }
  for (int m = 1; m < 64; m <<= 1) {
    s1 += __shfl_xor(s1, m, 64);
    s2 += __shfl_xor(s2, m, 64);
  }
  __shared__ float rs1[4], rs2[4], rdt[4];
  if (lane == 0) { rs1[wave] = s1; rs2[wave] = s2; }
  __syncthreads();
  s1 = rs1[0] + rs1[1] + rs1[2] + rs1[3];
  s2 = rs2[0] + rs2[1] + rs2[2] + rs2[3];
  float mean = s1 * (1.f / FD_SZ);
  float var = s2 * (1.f / FD_SZ) - mean * mean;
  float rstd = rsqrtf(var + 1e-5f);
  float dot = 0.f;
  float pn[3];
#pragma unroll
  for (int k = 0; k < 3; k++) {
    int c = tid + k * 256;
    pn[k] = (v[k] - mean) * rstd * ln2g[c] + ln2b[c];
    dot += pn[k] * xv[k];
  }
  for (int m = 1; m < 64; m <<= 1) dot += __shfl_xor(dot, m, 64);
  if (lane == 0) rdt[wave] = dot;
  __syncthreads();
  dot = rdt[0] + rdt[1] + rdt[2] + rdt[3];
  float gv = 1.f / (1.f + __expf(-dot * (1.0f / 27.712812921102035f)));  // /sqrt(768)
#pragma unroll
  for (int k = 0; k < 3; k++) {
    int c = tid + k * 256;
    out[(size_t)row * FD_SZ + c] = gv * xv[k] + (1.f - gv) * pn[k];
  }
}

// ---------------------------------------------------------------------------
extern "C" void kernel_launch(void* const* d_in, const int* in_sizes, int n_in,
                              void* d_out, int out_size, void* d_ws, size_t ws_size,
                              hipStream_t stream) {
  (void)in_sizes; (void)n_in; (void)out_size; (void)ws_size;
  const float* x = (const float*)d_in[0];
  const int* adj = (const int*)d_in[1];
  const float* W = (const float*)d_in[2];
  const float* a = (const float*)d_in[3];
  const float* log_unc = (const float*)d_in[4];
  const float* gate_w = (const float*)d_in[5];
  const float* gate_b = (const float*)d_in[6];
  const float* ln1g = (const float*)d_in[7];
  const float* ln1b = (const float*)d_in[8];
  const float* w1 = (const float*)d_in[9];
  const float* b1 = (const float*)d_in[10];
  const float* w2 = (const float*)d_in[11];
  const float* b2 = (const float*)d_in[12];
  const float* ln2g = (const float*)d_in[13];
  const float* ln2b = (const float*)d_in[14];

  // Workspace (liveness-overlapped):
  //  [0          ) Wt      1,769,472   -> adjm (96 KB) after vf GEMM
  //  [1,769,472  ) w1t     294,912
  //  [2,064,384  ) w2t     589,824
  //  [2,654,208  ) cg      6,144
  //  [2,660,352  ) e1      196,608   (e2 contiguous after -> one zero pass)
  //  [2,856,960  ) e2      196,608
  //  [15,636,480 ) vf      37,748,736 ; reused: t1bf / projbf
  // d_out (50.3 MB) triple-duty scratch: xb (bf16 x, 25.2 MB, live until vf
  // GEMM) -> pf (bf16 g-partials, 37.7 MB, attn -> t1 GEMM) -> final output.
  char* ws = (char*)d_ws;
  ushort_t* Wt      = (ushort_t*)(ws + 0);
  uint_t*   adjm    = (uint_t*)(ws + 0);            // over dead Wt (post-vf)
  ushort_t* w1t     = (ushort_t*)(ws + 1769472);
  ushort_t* w2t     = (ushort_t*)(ws + 2064384);
  float*    cg      = (float*)(ws + 2654208);
  float*    e1      = (float*)(ws + 2660352);
  float*    e2      = (float*)(ws + 2856960);
  ushort_t* vf      = (ushort_t*)(ws + 15636480);
  ushort_t* t1bf    = (ushort_t*)(ws + 15636480);   // over dead vf
  ushort_t* projbf  = (ushort_t*)(ws + 28219392);   // over dead vf
  ushort_t* xb      = (ushort_t*)d_out;             // scratch until vf GEMM
  ushort_t* pf      = (ushort_t*)d_out;             // scratch: attn partials

  transpose_tile<<<dim3(HD_SZ / 64, FD_SZ / 64, 3), 256, 0, stream>>>(W, Wt, FD_SZ, HD_SZ);
  transpose_tile<<<dim3(HD_SZ / 64, HD_SZ / 64, 1), 256, 0, stream>>>(w1, w1t, HD_SZ, HD_SZ);
  transpose_tile<<<dim3(FD_SZ / 64, HD_SZ / 64, 1), 256, 0, stream>>>(w2, w2t, HD_SZ, FD_SZ);

  // gates + x->bf16 downcast fused (gate touches every x element once)
  gate_kernel<<<dim3(N_SZ), 256, 0, stream>>>(x, gate_w, gate_b, cg, xb);

  // e1,e2 zero-init for atomic accumulation (contiguous 98304 floats)
  zero_kernel<<<dim3((2 * G_SZ * M_SZ) / 256), 256, 0, stream>>>(e1);

  // vf[g] = (x @ W[g]) in V-tile layout; epilogue also emits e1/e2
  gemm_kernel<false, true, false, true, true, false><<<dim3(3, 128, 3), 256, 0, stream>>>(
      xb, 0, Wt, (size_t)HD_SZ * FD_SZ, nullptr, vf, 0,
      M_SZ, FD_SZ, HD_SZ, a, e1, e2);

  // adj -> bitmask, into the now-dead Wt region (must follow the vf GEMM)
  pack_adj<<<dim3((G_SZ * N_SZ * N_SZ) / 256), 256, 0, stream>>>(adj, adjm);

  // split-g attention -> bf16 partials in d_out (xb dead after vf GEMM)
  attn_kernel<<<dim3(N_SZ / 32, B_SZ, G_SZ), 512, 0, stream>>>(
      adjm, vf, e1, e2, cg, log_unc, ln1g, ln1b, pf);

  // t1 = relu((sum_g pf[g]) @ w1 + b1); 3-slice sum folded into A-staging
  gemm_kernel<true, true, true, false, false, true><<<dim3(3, 128, 1), 256, 0, stream>>>(
      pf, 0, w1t, 0, b1, t1bf, 0, M_SZ, HD_SZ, HD_SZ, nullptr, nullptr, nullptr);
  // proj = t1 @ w2 + b2 (bf16 out)
  gemm_kernel<false, true, true, false, false, false><<<dim3(6, 128, 1), 256, 0, stream>>>(
      t1bf, 0, w2t, 0, b2, projbf, 0, M_SZ, HD_SZ, FD_SZ, nullptr, nullptr, nullptr);

  final_kernel<<<dim3(M_SZ), 256, 0, stream>>>(projbf, x, ln2g, ln2b, (float*)d_out);
}